// Round 2
// baseline (7232.684 us; speedup 1.0000x reference)
//
#include <hip/hip_runtime.h>

static constexpr int B_ = 256;
static constexpr int C_ = 384;
static constexpr int N_ = 196;   // 14*14
static constexpr int H_ = 14;
static constexpr int CH_ = 96;
static constexpr int PW_ = 49;   // pixels per 7x7 window
static constexpr int NPAIR_ = 1225; // 49*50/2 (i<=j pairs)

// ---------------- window selection: s[b,w] = sum triu(cos) -------------------
__global__ __launch_bounds__(256) void k_winsel(const float* __restrict__ x,
                                                float* __restrict__ swin) {
    int blk = blockIdx.x;            // b*4 + window
    int b = blk >> 2, wi = blk & 3;
    int hr = (wi >> 1) * 7, wc0 = (wi & 1) * 7;
    __shared__ float xs[128 * PW_];  // [cc][pixel]
    __shared__ float dots[NPAIR_];
    __shared__ float nrm[PW_];
    __shared__ float red[256];
    int tid = threadIdx.x;
    int pi[5], pj[5];
    int nm = 0;
    for (int p = tid; p < NPAIR_; p += 256) {
        int pp = p, i = 0;
        while (pp >= PW_ - i) { pp -= PW_ - i; ++i; }
        pi[nm] = i; pj[nm] = i + pp; ++nm;
    }
    float acc[5] = {0.f, 0.f, 0.f, 0.f, 0.f};
    for (int c0 = 0; c0 < C_; c0 += 128) {
        __syncthreads();
        for (int e = tid; e < 128 * PW_; e += 256) {
            int cc = e / PW_, i = e - cc * PW_;
            int h = hr + i / 7, w = wc0 + i % 7;
            xs[e] = x[((b * C_ + c0 + cc) * H_ + h) * H_ + w];
        }
        __syncthreads();
        for (int cc = 0; cc < 128; ++cc) {
            const float* row = &xs[cc * PW_];
            #pragma unroll
            for (int t = 0; t < 5; ++t)
                if (t < nm) acc[t] = fmaf(row[pi[t]], row[pj[t]], acc[t]);
        }
    }
    for (int t = 0; t < nm; ++t) dots[tid + t * 256] = acc[t];
    __syncthreads();
    if (tid < PW_) {
        int diag = tid * PW_ - tid * (tid - 1) / 2;  // pair (i,i)
        nrm[tid] = sqrtf(dots[diag]);
    }
    __syncthreads();
    float part = 0.f;
    for (int t = 0; t < nm; ++t) {
        float den = fmaxf(nrm[pi[t]] * nrm[pj[t]], 1e-8f);
        part += dots[tid + t * 256] / den;
    }
    red[tid] = part;
    __syncthreads();
    for (int st = 128; st > 0; st >>= 1) {
        if (tid < st) red[tid] += red[tid + st];
        __syncthreads();
    }
    if (tid == 0) swin[blk] = red[0];
}

// ---------------- top-2 windows -> masks ------------------------------------
__global__ __launch_bounds__(256) void k_mask(const float* __restrict__ swin,
                                              const void* __restrict__ gammp,
                                              float* __restrict__ mA,
                                              float* __restrict__ mB) {
    int b = blockIdx.x;
    float sv[4];
    #pragma unroll
    for (int i = 0; i < 4; ++i) sv[i] = swin[b * 4 + i];
    int i0 = 0; float bv = sv[0];
    #pragma unroll
    for (int i = 1; i < 4; ++i) if (sv[i] > bv) { bv = sv[i]; i0 = i; }
    int i1 = -1; float bv1 = -1e30f;
    #pragma unroll
    for (int i = 0; i < 4; ++i) {
        if (i == i0) continue;
        if (sv[i] > bv1) { bv1 = sv[i]; i1 = i; }
    }
    // gamm is a python int scalar; hedge against int32 vs float32 storage
    int iv = *(const int*)gammp;
    float g = (iv == 1) ? 1.0f : __int_as_float(iv);
    int n = threadIdx.x;
    if (n < N_) {
        int h = n / 14, w = n - h * 14;
        int widx = ((h >= 7) ? 2 : 0) + ((w >= 7) ? 1 : 0);
        bool member = (widx == i0) || (widx == i1);
        float a = member ? 0.f : 1.f;
        float bm = 1.f - a;
        if (b == 0) { a = g; bm = g; }
        mA[b * N_ + n] = a;
        mB[b * N_ + n] = bm;
    }
}

// -- q/k/v: out[bl,n,o] = m[bl,n]*(sum_c x[bl,c,n]*W[o,c]) + bias[o]
//    (x, mask pre-offset to the batch group; out is group-local)
__global__ __launch_bounds__(256) void k_qkv(const float* __restrict__ x,
                                             const float* __restrict__ W,
                                             const float* __restrict__ bias,
                                             const float* __restrict__ mask,
                                             float* __restrict__ out) {
    int b = blockIdx.x, n0 = blockIdx.y * 64, o0 = blockIdx.z * 64;
    __shared__ float xs[16][65];
    __shared__ float ws[64][17];
    int tid = threadIdx.x, tx = tid & 15, ty = tid >> 4;
    float acc[4][4] = {};
    for (int c0 = 0; c0 < C_; c0 += 16) {
        __syncthreads();
        for (int e = tid; e < 1024; e += 256) {
            int cc = e >> 6, nn = e & 63;
            int n = n0 + nn;
            xs[cc][nn] = (n < N_) ? x[(b * C_ + c0 + cc) * N_ + n] : 0.f;
        }
        for (int e = tid; e < 1024; e += 256) {
            int oo = e >> 4, cc = e & 15;
            ws[oo][cc] = W[(o0 + oo) * C_ + c0 + cc];
        }
        __syncthreads();
        #pragma unroll
        for (int cc = 0; cc < 16; ++cc) {
            float a[4], bb[4];
            #pragma unroll
            for (int i = 0; i < 4; ++i) a[i] = xs[cc][ty * 4 + i];
            #pragma unroll
            for (int j = 0; j < 4; ++j) bb[j] = ws[tx * 4 + j][cc];
            #pragma unroll
            for (int i = 0; i < 4; ++i)
                #pragma unroll
                for (int j = 0; j < 4; ++j) acc[i][j] = fmaf(a[i], bb[j], acc[i][j]);
        }
    }
    #pragma unroll
    for (int i = 0; i < 4; ++i) {
        int n = n0 + ty * 4 + i;
        if (n >= N_) continue;
        float m = mask ? mask[b * N_ + n] : 1.f;
        #pragma unroll
        for (int j = 0; j < 4; ++j) {
            int o = o0 + tx * 4 + j;
            out[(b * N_ + n) * C_ + o] = m * acc[i][j] + bias[o];
        }
    }
}

// ---------------- attn[bl,i,j] = sum_c q[bl,i,c]*k[bl,j,c] ------------------
__global__ __launch_bounds__(256) void k_attn(const float* __restrict__ q,
                                              const float* __restrict__ k,
                                              float* __restrict__ attn) {
    int b = blockIdx.x, i0 = blockIdx.y * 64, j0 = blockIdx.z * 64;
    __shared__ float qs[64][17];
    __shared__ float ks[64][17];
    int tid = threadIdx.x, tx = tid & 15, ty = tid >> 4;
    float acc[4][4] = {};
    for (int c0 = 0; c0 < C_; c0 += 16) {
        __syncthreads();
        for (int e = tid; e < 1024; e += 256) {
            int r = e >> 4, cc = e & 15;
            int i = i0 + r;
            qs[r][cc] = (i < N_) ? q[(b * N_ + i) * C_ + c0 + cc] : 0.f;
            int j = j0 + r;
            ks[r][cc] = (j < N_) ? k[(b * N_ + j) * C_ + c0 + cc] : 0.f;
        }
        __syncthreads();
        #pragma unroll
        for (int cc = 0; cc < 16; ++cc) {
            float a[4], bb[4];
            #pragma unroll
            for (int i = 0; i < 4; ++i) a[i] = qs[ty * 4 + i][cc];
            #pragma unroll
            for (int j = 0; j < 4; ++j) bb[j] = ks[tx * 4 + j][cc];
            #pragma unroll
            for (int i = 0; i < 4; ++i)
                #pragma unroll
                for (int j = 0; j < 4; ++j) acc[i][j] = fmaf(a[i], bb[j], acc[i][j]);
        }
    }
    #pragma unroll
    for (int i = 0; i < 4; ++i) {
        int ii = i0 + ty * 4 + i;
        if (ii >= N_) continue;
        #pragma unroll
        for (int j = 0; j < 4; ++j) {
            int jj = j0 + tx * 4 + j;
            if (jj < N_) attn[(b * N_ + ii) * N_ + jj] = acc[i][j];
        }
    }
}

// ---------------- spa[row] = mean_j attn[row, j] (group-local) --------------
__global__ __launch_bounds__(256) void k_spa(const float* __restrict__ attn,
                                             float* __restrict__ spa) {
    int row = blockIdx.x;
    const float* rp = attn + (size_t)row * N_;
    int t = threadIdx.x;
    float v = (t < N_) ? rp[t] : 0.f;
    __shared__ float red[256];
    red[t] = v; __syncthreads();
    for (int st = 128; st > 0; st >>= 1) {
        if (t < st) red[t] += red[t + st];
        __syncthreads();
    }
    if (t == 0) spa[row] = red[0] / (float)N_;
}

// ---------------- spatial-sim weight, in-place over attn row ----------------
__global__ __launch_bounds__(256) void k_weight(float* __restrict__ attn,
                                                const float* __restrict__ spa) {
    int row = blockIdx.x;            // bl*N + i
    int b = row / N_, i = row - b * N_;
    int t = threadIdx.x;
    __shared__ float osp[N_];
    __shared__ float red[256];
    __shared__ float lastsh;
    float myspa = spa[row];
    float o = 0.f;
    if (t < N_) { o = fabsf(myspa - spa[b * N_ + t]); osp[t] = o; }
    __syncthreads();
    if (t < N_) {
        int cgt = 0, ceq = 0;
        for (int j = 0; j < N_; ++j) {
            float oj = osp[j];
            cgt += (oj > o) ? 1 : 0;
            ceq += (oj == o) ? 1 : 0;
        }
        // value at descending-sorted position 97 (98th largest, tie-exact)
        if (cgt <= 97 && cgt + ceq >= 98) lastsh = o;
    }
    __syncthreads();
    float last = lastsh;
    float* rowp = attn + (size_t)row * N_;
    float s = (t < N_) ? rowp[t] : 0.f;
    float a1 = -1e30f, a2 = -1e30f;
    if (t < N_) {
        float of = o + ((t == i) ? 10000.f : 0.f);
        float o1 = (of < last) ? 0.f : 1.f;
        float o2 = (o1 > last) ? 0.f : 1.f;   // note: compares the 0/1 matrix (faithful)
        float w1 = o1 * s;
        float w2 = o2 * s;
        a1 = (w1 == 0.f) ? -100.f : w1;
        a2 = (w2 == 0.f) ? -100.f : w2;
    }
    // softmax 1
    red[t] = a1; __syncthreads();
    for (int st = 128; st > 0; st >>= 1) {
        if (t < st) red[t] = fmaxf(red[t], red[t + st]);
        __syncthreads();
    }
    float m1 = red[0]; __syncthreads();
    float e1 = (t < N_) ? expf(a1 - m1) : 0.f;
    red[t] = e1; __syncthreads();
    for (int st = 128; st > 0; st >>= 1) {
        if (t < st) red[t] += red[t + st];
        __syncthreads();
    }
    float S1 = red[0]; __syncthreads();
    // softmax 2
    red[t] = a2; __syncthreads();
    for (int st = 128; st > 0; st >>= 1) {
        if (t < st) red[t] = fmaxf(red[t], red[t + st]);
        __syncthreads();
    }
    float m2 = red[0]; __syncthreads();
    float e2 = (t < N_) ? expf(a2 - m2) : 0.f;
    red[t] = e2; __syncthreads();
    for (int st = 128; st > 0; st >>= 1) {
        if (t < st) red[t] += red[t + st];
        __syncthreads();
    }
    float S2 = red[0]; __syncthreads();
    if (t < N_) rowp[t] = e1 / S1 + e2 / S2;
}

// ---------------- feat[bl,i,c] = sum_j w[bl,i,j]*v[bl,j,c] ------------------
__global__ __launch_bounds__(256) void k_feat(const float* __restrict__ w,
                                              const float* __restrict__ v,
                                              float* __restrict__ feat) {
    int b = blockIdx.x, i0 = blockIdx.y * 64, c0 = blockIdx.z * 64;
    __shared__ float wt[64][17];
    __shared__ float vt[16][65];
    int tid = threadIdx.x, tx = tid & 15, ty = tid >> 4;
    float acc[4][4] = {};
    for (int j0 = 0; j0 < N_; j0 += 16) {
        __syncthreads();
        for (int e = tid; e < 1024; e += 256) {
            int r = e >> 4, jj = e & 15;
            int i = i0 + r, j = j0 + jj;
            wt[r][jj] = (i < N_ && j < N_) ? w[(b * N_ + i) * N_ + j] : 0.f;
        }
        for (int e = tid; e < 1024; e += 256) {
            int jj = e >> 6, cc = e & 63;
            int j = j0 + jj;
            vt[jj][cc] = (j < N_) ? v[(b * N_ + j) * C_ + c0 + cc] : 0.f;
        }
        __syncthreads();
        #pragma unroll
        for (int jj = 0; jj < 16; ++jj) {
            float a[4], bb[4];
            #pragma unroll
            for (int i = 0; i < 4; ++i) a[i] = wt[ty * 4 + i][jj];
            #pragma unroll
            for (int j = 0; j < 4; ++j) bb[j] = vt[jj][tx * 4 + j];
            #pragma unroll
            for (int i = 0; i < 4; ++i)
                #pragma unroll
                for (int j = 0; j < 4; ++j) acc[i][j] = fmaf(a[i], bb[j], acc[i][j]);
        }
    }
    #pragma unroll
    for (int i = 0; i < 4; ++i) {
        int ii = i0 + ty * 4 + i;
        if (ii >= N_) continue;
        #pragma unroll
        for (int j = 0; j < 4; ++j)
            feat[(b * N_ + ii) * C_ + c0 + tx * 4 + j] = acc[i][j];
    }
}

// -- fcout[bl,c,n] = sum_k feat[bl,n,k]*fcw[c,k] + fcb[c] (NCHW transpose) ---
__global__ __launch_bounds__(256) void k_fc(const float* __restrict__ feat,
                                            const float* __restrict__ fw,
                                            const float* __restrict__ fb,
                                            float* __restrict__ out) {
    int b = blockIdx.x, c0 = blockIdx.y * 64, n0 = blockIdx.z * 64;
    __shared__ float as[64][17];
    __shared__ float bs[64][17];
    int tid = threadIdx.x, tx = tid & 15, ty = tid >> 4;
    float acc[4][4] = {};
    for (int k0 = 0; k0 < C_; k0 += 16) {
        __syncthreads();
        for (int e = tid; e < 1024; e += 256) {
            int r = e >> 4, kk = e & 15;
            as[r][kk] = fw[(c0 + r) * C_ + k0 + kk];
            int n = n0 + r;
            bs[r][kk] = (n < N_) ? feat[(b * N_ + n) * C_ + k0 + kk] : 0.f;
        }
        __syncthreads();
        #pragma unroll
        for (int kk = 0; kk < 16; ++kk) {
            float a[4], bb[4];
            #pragma unroll
            for (int i = 0; i < 4; ++i) a[i] = as[ty * 4 + i][kk];
            #pragma unroll
            for (int j = 0; j < 4; ++j) bb[j] = bs[tx * 4 + j][kk];
            #pragma unroll
            for (int i = 0; i < 4; ++i)
                #pragma unroll
                for (int j = 0; j < 4; ++j) acc[i][j] = fmaf(a[i], bb[j], acc[i][j]);
        }
    }
    #pragma unroll
    for (int i = 0; i < 4; ++i) {
        int c = c0 + ty * 4 + i;
        #pragma unroll
        for (int j = 0; j < 4; ++j) {
            int n = n0 + tx * 4 + j;
            if (n < N_) out[(b * C_ + c) * N_ + n] = acc[i][j] + fb[c];
        }
    }
}

// ---------------- direct 3x3 conv, optional fused BN+ReLU on input ----------
// in/outp are pre-offset to the batch group; b = blockIdx.x is group-local.
template <int CIN>
__global__ __launch_bounds__(256) void k_conv3(const float* __restrict__ in,
                                               const float* __restrict__ wgt,
                                               const float* __restrict__ cb,
                                               const float* __restrict__ scale,
                                               const float* __restrict__ shift,
                                               float* __restrict__ outp,
                                               int coutTotal) {
    int b = blockIdx.x, o0 = blockIdx.y * 16;
    __shared__ float xt[32][N_];
    __shared__ float wt[16 * 32 * 9];
    int tid = threadIdx.x;
    float acc[16] = {};
    for (int c0 = 0; c0 < CIN; c0 += 32) {
        __syncthreads();
        for (int e = tid; e < 32 * N_; e += 256) {
            int cc = e / N_, n = e - cc * N_;
            float v = in[(b * CIN + c0 + cc) * N_ + n];
            if (scale) v = fmaxf(v * scale[c0 + cc] + shift[c0 + cc], 0.f);
            xt[cc][n] = v;
        }
        for (int e = tid; e < 16 * 32 * 9; e += 256) {
            int oo = e / 288, rem = e - oo * 288;  // rem = cc*9 + k
            wt[e] = wgt[((o0 + oo) * CIN + c0) * 9 + rem];
        }
        __syncthreads();
        if (tid < N_) {
            int h = tid / 14, w = tid - h * 14;
            for (int cc = 0; cc < 32; ++cc) {
                float nb[9];
                #pragma unroll
                for (int kh = -1; kh <= 1; ++kh)
                    #pragma unroll
                    for (int kw = -1; kw <= 1; ++kw) {
                        int hh = h + kh, ww = w + kw;
                        nb[(kh + 1) * 3 + kw + 1] =
                            (hh >= 0 && hh < 14 && ww >= 0 && ww < 14) ? xt[cc][hh * 14 + ww] : 0.f;
                    }
                #pragma unroll
                for (int oo = 0; oo < 16; ++oo) {
                    const float* wp = &wt[(oo * 32 + cc) * 9];
                    float s = 0.f;
                    #pragma unroll
                    for (int k2 = 0; k2 < 9; ++k2) s = fmaf(nb[k2], wp[k2], s);
                    acc[oo] += s;
                }
            }
        }
    }
    if (tid < N_) {
        #pragma unroll
        for (int oo = 0; oo < 16; ++oo)
            outp[(b * coutTotal + o0 + oo) * N_ + tid] = acc[oo] + cb[o0 + oo];
    }
}

// ---------------- BN train stats -> per-channel scale/shift -----------------
__global__ __launch_bounds__(256) void k_bnstat(const float* __restrict__ in,
                                                const float* __restrict__ g,
                                                const float* __restrict__ beta,
                                                float* __restrict__ scale,
                                                float* __restrict__ shift,
                                                int cch) {
    int c = blockIdx.x;
    double s = 0.0, s2 = 0.0;
    for (int idx = threadIdx.x; idx < B_ * N_; idx += 256) {
        int b = idx / N_, n = idx - b * N_;
        float v = in[(b * cch + c) * N_ + n];
        s += v;
        s2 += (double)v * v;
    }
    __shared__ double rs[256];
    __shared__ double rs2[256];
    rs[threadIdx.x] = s; rs2[threadIdx.x] = s2;
    __syncthreads();
    for (int st = 128; st > 0; st >>= 1) {
        if (threadIdx.x < st) {
            rs[threadIdx.x] += rs[threadIdx.x + st];
            rs2[threadIdx.x] += rs2[threadIdx.x + st];
        }
        __syncthreads();
    }
    if (threadIdx.x == 0) {
        double M = (double)B_ * N_;
        double mean = rs[0] / M;
        double var = rs2[0] / M - mean * mean;
        float sc = (float)((double)g[c] / sqrt(var + 1e-5));
        scale[c] = sc;
        shift[c] = beta[c] - (float)mean * sc;
    }
}

// ---------------- final BN2 + ReLU, in-place over d_out ---------------------
__global__ __launch_bounds__(256) void k_final(float* __restrict__ buf,
                                               const float* __restrict__ scale,
                                               const float* __restrict__ shift) {
    size_t total = (size_t)B_ * C_ * N_;
    for (size_t idx = (size_t)blockIdx.x * 256 + threadIdx.x; idx < total;
         idx += (size_t)gridDim.x * 256) {
        int c = (int)((idx / N_) % C_);
        buf[idx] = fmaxf(buf[idx] * scale[c] + shift[c], 0.f);
    }
}

extern "C" void kernel_launch(void* const* d_in, const int* in_sizes, int n_in,
                              void* d_out, int out_size, void* d_ws, size_t ws_size,
                              hipStream_t stream) {
    (void)in_sizes; (void)n_in; (void)out_size;
    const float* x    = (const float*)d_in[0];
    const float* qw   = (const float*)d_in[1];
    const float* qb   = (const float*)d_in[2];
    const float* kw   = (const float*)d_in[3];
    const float* kb   = (const float*)d_in[4];
    const float* vw   = (const float*)d_in[5];
    const float* vb   = (const float*)d_in[6];
    const float* fcw  = (const float*)d_in[7];
    const float* fcb  = (const float*)d_in[8];
    const float* c1w  = (const float*)d_in[9];
    const float* c1b  = (const float*)d_in[10];
    const float* bn1g = (const float*)d_in[11];
    const float* bn1b = (const float*)d_in[12];
    const float* c2w  = (const float*)d_in[13];
    const float* c2b  = (const float*)d_in[14];
    const float* bn2g = (const float*)d_in[15];
    const float* bn2b = (const float*)d_in[16];
    const void*  gam  = d_in[17];

    // --- adaptive batch-group size so the workspace layout FITS ws_size ---
    // needed(GB) = y1 + mA + mB + swin + bn + 2*GB*N*C (qh,kh) + GB*N*N + GB*N
    const size_t fixedF = (size_t)B_ * CH_ * N_ + 2 * (size_t)B_ * N_ + B_ * 4 + 960 + 64;
    int GB = 0;
    const int tiers[6] = {64, 32, 16, 8, 4, 2};
    for (int t = 0; t < 6; ++t) {
        int g = tiers[t];
        size_t needF = fixedF + 2 * (size_t)g * N_ * C_ + (size_t)g * N_ * N_ + (size_t)g * N_;
        if (needF * sizeof(float) <= ws_size) { GB = g; break; }
    }
    if (GB == 0) GB = 1;  // last resort; 1 divides 256

    float* wsf   = (float*)d_ws;
    float* y1    = wsf;                                   // B*CH*N (full, raw conv1 out)
    float* mA    = y1 + (size_t)B_ * CH_ * N_;            // B*N
    float* mB    = mA + (size_t)B_ * N_;                  // B*N
    float* swin  = mB + (size_t)B_ * N_;                  // B*4
    float* bnbuf = swin + B_ * 4;                         // 960
    float* scale1 = bnbuf, *shift1 = bnbuf + 96, *scale2 = bnbuf + 192, *shift2 = bnbuf + 576;
    float* qh    = bnbuf + 960 + 64;                      // GB*N*C  (q -> v -> fcout)
    float* kh    = qh + (size_t)GB * N_ * C_;             // GB*N*C  (k -> feat)
    float* attnh = kh + (size_t)GB * N_ * C_;             // GB*N*N  (attn -> w)
    float* spah  = attnh + (size_t)GB * N_ * N_;          // GB*N

    float* yout = (float*)d_out;   // raw conv2 output lives in d_out, BN2+ReLU in-place

    k_winsel<<<dim3(B_ * 4), 256, 0, stream>>>(x, swin);
    k_mask<<<dim3(B_), 256, 0, stream>>>(swin, gam, mA, mB);

    for (int b0 = 0; b0 < B_; b0 += GB) {
        const float* xg = x + (size_t)b0 * C_ * N_;
        k_qkv<<<dim3(GB, 4, 6), 256, 0, stream>>>(xg, qw, qb, mA + (size_t)b0 * N_, qh);
        k_qkv<<<dim3(GB, 4, 6), 256, 0, stream>>>(xg, kw, kb, mB + (size_t)b0 * N_, kh);
        k_attn<<<dim3(GB, 4, 4), 256, 0, stream>>>(qh, kh, attnh);
        k_spa<<<dim3(GB * N_), 256, 0, stream>>>(attnh, spah);
        k_weight<<<dim3(GB * N_), 256, 0, stream>>>(attnh, spah);
        k_qkv<<<dim3(GB, 4, 6), 256, 0, stream>>>(xg, vw, vb, nullptr, qh);     // v (q dead)
        k_feat<<<dim3(GB, 4, 6), 256, 0, stream>>>(attnh, qh, kh);              // feat (k dead)
        k_fc<<<dim3(GB, 6, 4), 256, 0, stream>>>(kh, fcw, fcb, qh);             // fcout (v dead)
        k_conv3<384><<<dim3(GB, 6), 256, 0, stream>>>(qh, c1w, c1b, nullptr, nullptr,
                                                      y1 + (size_t)b0 * CH_ * N_, CH_);
    }
    k_bnstat<<<dim3(CH_), 256, 0, stream>>>(y1, bn1g, bn1b, scale1, shift1, CH_);
    for (int b0 = 0; b0 < B_; b0 += GB) {
        k_conv3<96><<<dim3(GB, 24), 256, 0, stream>>>(y1 + (size_t)b0 * CH_ * N_,
                                                      c2w, c2b, scale1, shift1,
                                                      yout + (size_t)b0 * C_ * N_, C_);
    }
    k_bnstat<<<dim3(C_), 256, 0, stream>>>(yout, bn2g, bn2b, scale2, shift2, C_);
    k_final<<<dim3(18816), 256, 0, stream>>>(yout, scale2, shift2);
}

// Round 3
// 3900.114 us; speedup vs baseline: 1.8545x; 1.8545x over previous
//
#include <hip/hip_runtime.h>

static constexpr int B_ = 256;
static constexpr int C_ = 384;
static constexpr int N_ = 196;   // 14*14
static constexpr int H_ = 14;
static constexpr int CH_ = 96;
static constexpr int PW_ = 49;   // pixels per 7x7 window
static constexpr int NPAIR_ = 1225; // 49*50/2 (i<=j pairs)

using bf8 = __attribute__((ext_vector_type(8))) short;   // 8 bf16 (4 VGPR)
using f4  = __attribute__((ext_vector_type(4))) float;   // 4 f32 acc

__device__ __forceinline__ float bf2f(unsigned short u) {
    unsigned int x = ((unsigned int)u) << 16;
    return __builtin_bit_cast(float, x);
}
__device__ __forceinline__ unsigned short f2bf(float f) {
    unsigned int x = __builtin_bit_cast(unsigned int, f);
    x = x + 0x7FFFu + ((x >> 16) & 1u);   // RNE
    return (unsigned short)(x >> 16);
}

// ---------------- window selection: s[b,w] = sum triu(cos) -------------------
__global__ __launch_bounds__(256) void k_winsel(const float* __restrict__ x,
                                                float* __restrict__ swin) {
    int blk = blockIdx.x;            // b*4 + window
    int b = blk >> 2, wi = blk & 3;
    int hr = (wi >> 1) * 7, wc0 = (wi & 1) * 7;
    __shared__ float xs[128 * PW_];
    __shared__ float dots[NPAIR_];
    __shared__ float nrm[PW_];
    __shared__ float red[256];
    int tid = threadIdx.x;
    int pi[5], pj[5];
    int nm = 0;
    for (int p = tid; p < NPAIR_; p += 256) {
        int pp = p, i = 0;
        while (pp >= PW_ - i) { pp -= PW_ - i; ++i; }
        pi[nm] = i; pj[nm] = i + pp; ++nm;
    }
    float acc[5] = {0.f, 0.f, 0.f, 0.f, 0.f};
    for (int c0 = 0; c0 < C_; c0 += 128) {
        __syncthreads();
        for (int e = tid; e < 128 * PW_; e += 256) {
            int cc = e / PW_, i = e - cc * PW_;
            int h = hr + i / 7, w = wc0 + i % 7;
            xs[e] = x[((b * C_ + c0 + cc) * H_ + h) * H_ + w];
        }
        __syncthreads();
        for (int cc = 0; cc < 128; ++cc) {
            const float* row = &xs[cc * PW_];
            #pragma unroll
            for (int t = 0; t < 5; ++t)
                if (t < nm) acc[t] = fmaf(row[pi[t]], row[pj[t]], acc[t]);
        }
    }
    for (int t = 0; t < nm; ++t) dots[tid + t * 256] = acc[t];
    __syncthreads();
    if (tid < PW_) {
        int diag = tid * PW_ - tid * (tid - 1) / 2;
        nrm[tid] = sqrtf(dots[diag]);
    }
    __syncthreads();
    float part = 0.f;
    for (int t = 0; t < nm; ++t) {
        float den = fmaxf(nrm[pi[t]] * nrm[pj[t]], 1e-8f);
        part += dots[tid + t * 256] / den;
    }
    red[tid] = part;
    __syncthreads();
    for (int st = 128; st > 0; st >>= 1) {
        if (tid < st) red[tid] += red[tid + st];
        __syncthreads();
    }
    if (tid == 0) swin[blk] = red[0];
}

// ---------------- top-2 windows -> masks ------------------------------------
__global__ __launch_bounds__(256) void k_mask(const float* __restrict__ swin,
                                              const void* __restrict__ gammp,
                                              float* __restrict__ mA,
                                              float* __restrict__ mB) {
    int b = blockIdx.x;
    float sv[4];
    #pragma unroll
    for (int i = 0; i < 4; ++i) sv[i] = swin[b * 4 + i];
    int i0 = 0; float bv = sv[0];
    #pragma unroll
    for (int i = 1; i < 4; ++i) if (sv[i] > bv) { bv = sv[i]; i0 = i; }
    int i1 = -1; float bv1 = -1e30f;
    #pragma unroll
    for (int i = 0; i < 4; ++i) {
        if (i == i0) continue;
        if (sv[i] > bv1) { bv1 = sv[i]; i1 = i; }
    }
    int iv = *(const int*)gammp;
    float g = (iv == 1) ? 1.0f : __int_as_float(iv);
    int n = threadIdx.x;
    if (n < N_) {
        int h = n / 14, w = n - h * 14;
        int widx = ((h >= 7) ? 2 : 0) + ((w >= 7) ? 1 : 0);
        bool member = (widx == i0) || (widx == i1);
        float a = member ? 0.f : 1.f;
        float bm = 1.f - a;
        if (b == 0) { a = g; bm = g; }
        mA[b * N_ + n] = a;
        mB[b * N_ + n] = bm;
    }
}

// -- q/k/v: out[bl,n,o] = m[bl,n]*(sum_c x[bl,c,n]*W[o,c]) + bias[o] ---------
__global__ __launch_bounds__(256) void k_qkv(const float* __restrict__ x,
                                             const float* __restrict__ W,
                                             const float* __restrict__ bias,
                                             const float* __restrict__ mask,
                                             float* __restrict__ out) {
    int b = blockIdx.x, n0 = blockIdx.y * 64, o0 = blockIdx.z * 64;
    __shared__ float xs[16][65];
    __shared__ float ws[64][17];
    int tid = threadIdx.x, tx = tid & 15, ty = tid >> 4;
    float acc[4][4] = {};
    for (int c0 = 0; c0 < C_; c0 += 16) {
        __syncthreads();
        for (int e = tid; e < 1024; e += 256) {
            int cc = e >> 6, nn = e & 63;
            int n = n0 + nn;
            xs[cc][nn] = (n < N_) ? x[(b * C_ + c0 + cc) * N_ + n] : 0.f;
        }
        for (int e = tid; e < 1024; e += 256) {
            int oo = e >> 4, cc = e & 15;
            ws[oo][cc] = W[(o0 + oo) * C_ + c0 + cc];
        }
        __syncthreads();
        #pragma unroll
        for (int cc = 0; cc < 16; ++cc) {
            float a[4], bb[4];
            #pragma unroll
            for (int i = 0; i < 4; ++i) a[i] = xs[cc][ty * 4 + i];
            #pragma unroll
            for (int j = 0; j < 4; ++j) bb[j] = ws[tx * 4 + j][cc];
            #pragma unroll
            for (int i = 0; i < 4; ++i)
                #pragma unroll
                for (int j = 0; j < 4; ++j) acc[i][j] = fmaf(a[i], bb[j], acc[i][j]);
        }
    }
    #pragma unroll
    for (int i = 0; i < 4; ++i) {
        int n = n0 + ty * 4 + i;
        if (n >= N_) continue;
        float m = mask ? mask[b * N_ + n] : 1.f;
        #pragma unroll
        for (int j = 0; j < 4; ++j) {
            int o = o0 + tx * 4 + j;
            out[(b * N_ + n) * C_ + o] = m * acc[i][j] + bias[o];
        }
    }
}

// ---------------- attn[bl,i,j] = sum_c q[bl,i,c]*k[bl,j,c] ------------------
__global__ __launch_bounds__(256) void k_attn(const float* __restrict__ q,
                                              const float* __restrict__ k,
                                              float* __restrict__ attn) {
    int b = blockIdx.x, i0 = blockIdx.y * 64, j0 = blockIdx.z * 64;
    __shared__ float qs[64][17];
    __shared__ float ks[64][17];
    int tid = threadIdx.x, tx = tid & 15, ty = tid >> 4;
    float acc[4][4] = {};
    for (int c0 = 0; c0 < C_; c0 += 16) {
        __syncthreads();
        for (int e = tid; e < 1024; e += 256) {
            int r = e >> 4, cc = e & 15;
            int i = i0 + r;
            qs[r][cc] = (i < N_) ? q[(b * N_ + i) * C_ + c0 + cc] : 0.f;
            int j = j0 + r;
            ks[r][cc] = (j < N_) ? k[(b * N_ + j) * C_ + c0 + cc] : 0.f;
        }
        __syncthreads();
        #pragma unroll
        for (int cc = 0; cc < 16; ++cc) {
            float a[4], bb[4];
            #pragma unroll
            for (int i = 0; i < 4; ++i) a[i] = qs[ty * 4 + i][cc];
            #pragma unroll
            for (int j = 0; j < 4; ++j) bb[j] = ks[tx * 4 + j][cc];
            #pragma unroll
            for (int i = 0; i < 4; ++i)
                #pragma unroll
                for (int j = 0; j < 4; ++j) acc[i][j] = fmaf(a[i], bb[j], acc[i][j]);
        }
    }
    #pragma unroll
    for (int i = 0; i < 4; ++i) {
        int ii = i0 + ty * 4 + i;
        if (ii >= N_) continue;
        #pragma unroll
        for (int j = 0; j < 4; ++j) {
            int jj = j0 + tx * 4 + j;
            if (jj < N_) attn[(b * N_ + ii) * N_ + jj] = acc[i][j];
        }
    }
}

// ---------------- spa[row] = mean_j attn[row, j] ----------------------------
__global__ __launch_bounds__(256) void k_spa(const float* __restrict__ attn,
                                             float* __restrict__ spa) {
    int row = blockIdx.x;
    const float* rp = attn + (size_t)row * N_;
    int t = threadIdx.x;
    float v = (t < N_) ? rp[t] : 0.f;
    __shared__ float red[256];
    red[t] = v; __syncthreads();
    for (int st = 128; st > 0; st >>= 1) {
        if (t < st) red[t] += red[t + st];
        __syncthreads();
    }
    if (t == 0) spa[row] = red[0] / (float)N_;
}

// ---------------- spatial-sim weight, in-place over attn row ----------------
__global__ __launch_bounds__(256) void k_weight(float* __restrict__ attn,
                                                const float* __restrict__ spa) {
    int row = blockIdx.x;
    int b = row / N_, i = row - b * N_;
    int t = threadIdx.x;
    __shared__ float osp[N_];
    __shared__ float red[256];
    __shared__ float lastsh;
    float myspa = spa[row];
    float o = 0.f;
    if (t < N_) { o = fabsf(myspa - spa[b * N_ + t]); osp[t] = o; }
    __syncthreads();
    if (t < N_) {
        int cgt = 0, ceq = 0;
        for (int j = 0; j < N_; ++j) {
            float oj = osp[j];
            cgt += (oj > o) ? 1 : 0;
            ceq += (oj == o) ? 1 : 0;
        }
        if (cgt <= 97 && cgt + ceq >= 98) lastsh = o;
    }
    __syncthreads();
    float last = lastsh;
    float* rowp = attn + (size_t)row * N_;
    float s = (t < N_) ? rowp[t] : 0.f;
    float a1 = -1e30f, a2 = -1e30f;
    if (t < N_) {
        float of = o + ((t == i) ? 10000.f : 0.f);
        float o1 = (of < last) ? 0.f : 1.f;
        float o2 = (o1 > last) ? 0.f : 1.f;
        float w1 = o1 * s;
        float w2 = o2 * s;
        a1 = (w1 == 0.f) ? -100.f : w1;
        a2 = (w2 == 0.f) ? -100.f : w2;
    }
    red[t] = a1; __syncthreads();
    for (int st = 128; st > 0; st >>= 1) {
        if (t < st) red[t] = fmaxf(red[t], red[t + st]);
        __syncthreads();
    }
    float m1 = red[0]; __syncthreads();
    float e1 = (t < N_) ? expf(a1 - m1) : 0.f;
    red[t] = e1; __syncthreads();
    for (int st = 128; st > 0; st >>= 1) {
        if (t < st) red[t] += red[t + st];
        __syncthreads();
    }
    float S1 = red[0]; __syncthreads();
    red[t] = a2; __syncthreads();
    for (int st = 128; st > 0; st >>= 1) {
        if (t < st) red[t] = fmaxf(red[t], red[t + st]);
        __syncthreads();
    }
    float m2 = red[0]; __syncthreads();
    float e2 = (t < N_) ? expf(a2 - m2) : 0.f;
    red[t] = e2; __syncthreads();
    for (int st = 128; st > 0; st >>= 1) {
        if (t < st) red[t] += red[t + st];
        __syncthreads();
    }
    float S2 = red[0]; __syncthreads();
    if (t < N_) rowp[t] = e1 / S1 + e2 / S2;
}

// ---------------- feat[bl,i,c] = sum_j w[bl,i,j]*v[bl,j,c] ------------------
__global__ __launch_bounds__(256) void k_feat(const float* __restrict__ w,
                                              const float* __restrict__ v,
                                              float* __restrict__ feat) {
    int b = blockIdx.x, i0 = blockIdx.y * 64, c0 = blockIdx.z * 64;
    __shared__ float wt[64][17];
    __shared__ float vt[16][65];
    int tid = threadIdx.x, tx = tid & 15, ty = tid >> 4;
    float acc[4][4] = {};
    for (int j0 = 0; j0 < N_; j0 += 16) {
        __syncthreads();
        for (int e = tid; e < 1024; e += 256) {
            int r = e >> 4, jj = e & 15;
            int i = i0 + r, j = j0 + jj;
            wt[r][jj] = (i < N_ && j < N_) ? w[(b * N_ + i) * N_ + j] : 0.f;
        }
        for (int e = tid; e < 1024; e += 256) {
            int jj = e >> 6, cc = e & 63;
            int j = j0 + jj;
            vt[jj][cc] = (j < N_) ? v[(b * N_ + j) * C_ + c0 + cc] : 0.f;
        }
        __syncthreads();
        #pragma unroll
        for (int jj = 0; jj < 16; ++jj) {
            float a[4], bb[4];
            #pragma unroll
            for (int i = 0; i < 4; ++i) a[i] = wt[ty * 4 + i][jj];
            #pragma unroll
            for (int j = 0; j < 4; ++j) bb[j] = vt[jj][tx * 4 + j];
            #pragma unroll
            for (int i = 0; i < 4; ++i)
                #pragma unroll
                for (int j = 0; j < 4; ++j) acc[i][j] = fmaf(a[i], bb[j], acc[i][j]);
        }
    }
    #pragma unroll
    for (int i = 0; i < 4; ++i) {
        int ii = i0 + ty * 4 + i;
        if (ii >= N_) continue;
        #pragma unroll
        for (int j = 0; j < 4; ++j)
            feat[(b * N_ + ii) * C_ + c0 + tx * 4 + j] = acc[i][j];
    }
}

// -- fc: out NHWC bf16: outb[bl][n][c] = sum_k feat[bl,n,k]*fcw[c,k] + fcb[c]
__global__ __launch_bounds__(256) void k_fc(const float* __restrict__ feat,
                                            const float* __restrict__ fw,
                                            const float* __restrict__ fb,
                                            unsigned short* __restrict__ outb) {
    int b = blockIdx.x, c0 = blockIdx.y * 64, n0 = blockIdx.z * 64;
    __shared__ float as[64][17];
    __shared__ float bs[64][17];
    int tid = threadIdx.x, tx = tid & 15, ty = tid >> 4;
    float acc[4][4] = {};
    for (int k0 = 0; k0 < C_; k0 += 16) {
        __syncthreads();
        for (int e = tid; e < 1024; e += 256) {
            int r = e >> 4, kk = e & 15;
            as[r][kk] = fw[(c0 + r) * C_ + k0 + kk];
            int n = n0 + r;
            bs[r][kk] = (n < N_) ? feat[(b * N_ + n) * C_ + k0 + kk] : 0.f;
        }
        __syncthreads();
        #pragma unroll
        for (int kk = 0; kk < 16; ++kk) {
            float a[4], bb[4];
            #pragma unroll
            for (int i = 0; i < 4; ++i) a[i] = as[ty * 4 + i][kk];
            #pragma unroll
            for (int j = 0; j < 4; ++j) bb[j] = bs[tx * 4 + j][kk];
            #pragma unroll
            for (int i = 0; i < 4; ++i)
                #pragma unroll
                for (int j = 0; j < 4; ++j) acc[i][j] = fmaf(a[i], bb[j], acc[i][j]);
        }
    }
    #pragma unroll
    for (int j = 0; j < 4; ++j) {
        int n = n0 + tx * 4 + j;
        if (n < N_) {
            unsigned long long pk = 0ull;
            #pragma unroll
            for (int i = 0; i < 4; ++i) {
                int c = c0 + ty * 4 + i;
                pk |= ((unsigned long long)f2bf(acc[i][j] + fb[c])) << (16 * i);
            }
            *(unsigned long long*)&outb[((size_t)b * N_ + n) * C_ + c0 + ty * 4] = pk;
        }
    }
}

// ---------------- weight reorder to bf16 [o][tap*CIN + c] -------------------
__global__ __launch_bounds__(256) void k_wprep(const float* __restrict__ c1w,
                                               const float* __restrict__ c2w,
                                               unsigned short* __restrict__ W1,
                                               unsigned short* __restrict__ W2) {
    int i = blockIdx.x * 256 + threadIdx.x;
    if (i < 96 * 3456) {
        int o = i / 3456, r = i - o * 3456;
        int tap = r / 384, c = r - tap * 384;
        W1[i] = f2bf(c1w[(o * 384 + c) * 9 + tap]);
        return;
    }
    i -= 96 * 3456;
    if (i < 384 * 864) {
        int o = i / 864, r = i - o * 864;
        int tap = r / 96, c = r - tap * 96;
        W2[i] = f2bf(c2w[(o * 96 + c) * 9 + tap]);
    }
}

// ---------------- MFMA implicit-im2col 3x3 conv -----------------------------
// in: bf16 NHWC [b][196][CIN] (pre-offset). A = Wp [COUT][9*CIN].
// TRANS: apply per-input-channel scale/shift + relu while staging (BN1 fold).
// OUTBF: store bf16 NHWC [b][196][COUT]; else f32 NCHW [b][COUT][196].
// Epilogue: adds bias and atomically accumulates per-out-channel sum/sumsq.
template <int CIN, int COUT, bool TRANS, bool OUTBF>
__global__ __launch_bounds__(256) void k_convm(
    const unsigned short* __restrict__ in,
    const unsigned short* __restrict__ Wp,
    const float* __restrict__ cb,
    const float* __restrict__ scale,
    const float* __restrict__ shift,
    unsigned short* __restrict__ outb,
    float* __restrict__ outf,
    float* __restrict__ ssum, float* __restrict__ ssq) {
    constexpr int NP = 224;            // 196 padded to 14 frags of 16
    constexpr int CPT = CIN / 32;      // K-chunks per tap
    constexpr int KST = CPT * 9;
    int b = blockIdx.x, o0 = blockIdx.y * 32;
    __shared__ unsigned short As[32 * 32];   // [o][k]   2 KB
    __shared__ unsigned short Bs[NP * 32];   // [px][k] 14 KB
    int tid = threadIdx.x;
    int lane = tid & 63, wid = tid >> 6;
    int wo = wid & 1, wn = wid >> 1;         // wave tile: 16 o x 112 px
    int col = lane & 15, rowg = lane >> 4;
    f4 acc[7];
    #pragma unroll
    for (int f = 0; f < 7; ++f) acc[f] = (f4){0.f, 0.f, 0.f, 0.f};

    int c4 = (tid & 7) << 2;   // this thread's 4-channel slot (constant)
    int px0 = tid >> 3;        // 0..31; px = px0 + 32*i

    float sclA[3][4], shfA[3][4];
    if constexpr (TRANS) {
        static_assert(CPT <= 3, "TRANS preload sized for CIN<=96");
        #pragma unroll
        for (int q = 0; q < CPT; ++q)
            #pragma unroll
            for (int j = 0; j < 4; ++j) {
                int c = (q << 5) + c4 + j;
                sclA[q][j] = scale[c];
                shfA[q][j] = shift[c];
            }
    }

    for (int s = 0; s < KST; ++s) {
        int tap = s / CPT, q = s - tap * CPT;
        int c0 = q << 5;
        int dh = tap / 3 - 1, dw = tap % 3 - 1;
        __syncthreads();
        if (tid < 128) {   // stage A: 32 o x 32 k
            int o = tid >> 2, k8 = (tid & 3) << 3;
            const unsigned short* sp =
                Wp + (size_t)(o0 + o) * (9 * CIN) + tap * CIN + c0 + k8;
            *(int4*)&As[(o << 5) + k8] = *(const int4*)sp;
        }
        #pragma unroll
        for (int i = 0; i < 7; ++i) {   // stage B: 224 px x 32 k
            int px = px0 + (i << 5);
            int h = px / 14, w = px - h * 14;
            int hh = h + dh, w2 = w + dw;
            unsigned long long vv = 0ull;
            if (px < 196 && (unsigned)hh < 14u && (unsigned)w2 < 14u) {
                const unsigned short* sp =
                    in + ((size_t)b * 196 + hh * 14 + w2) * CIN + c0 + c4;
                unsigned long long raw = *(const unsigned long long*)sp;
                if constexpr (TRANS) {
                    unsigned long long ov = 0ull;
                    #pragma unroll
                    for (int j = 0; j < 4; ++j) {
                        float v = bf2f((unsigned short)(raw >> (16 * j)));
                        v = fmaxf(fmaf(v, sclA[q][j], shfA[q][j]), 0.f);
                        ov |= ((unsigned long long)f2bf(v)) << (16 * j);
                    }
                    vv = ov;
                } else {
                    vv = raw;
                }
            }
            *(unsigned long long*)&Bs[(px << 5) + c4] = vv;
        }
        __syncthreads();
        bf8 af = *(const bf8*)&As[(((wo << 4) + col) << 5) + (rowg << 3)];
        #pragma unroll
        for (int f = 0; f < 7; ++f) {
            bf8 bfv = *(const bf8*)&Bs[((wn * 112 + (f << 4) + col) << 5) + (rowg << 3)];
            acc[f] = __builtin_amdgcn_mfma_f32_16x16x32_bf16(af, bfv, acc[f], 0, 0, 0);
        }
    }

    // epilogue: bias, store, BN stat partials
    float bias[4];
    #pragma unroll
    for (int r = 0; r < 4; ++r) bias[r] = cb[o0 + (wo << 4) + (rowg << 2) + r];
    float s1[4] = {0.f, 0.f, 0.f, 0.f}, s2[4] = {0.f, 0.f, 0.f, 0.f};
    #pragma unroll
    for (int f = 0; f < 7; ++f) {
        int px = wn * 112 + (f << 4) + col;
        bool pv = px < 196;
        #pragma unroll
        for (int r = 0; r < 4; ++r) {
            float val = acc[f][r] + bias[r];
            if (pv) {
                int o = o0 + (wo << 4) + (rowg << 2) + r;
                if constexpr (OUTBF)
                    outb[((size_t)b * 196 + px) * COUT + o] = f2bf(val);
                else
                    outf[((size_t)b * COUT + o) * 196 + px] = val;
                s1[r] += val;
                s2[r] += val * val;
            }
        }
    }
    #pragma unroll
    for (int r = 0; r < 4; ++r) {
        float a = s1[r], c = s2[r];
        #pragma unroll
        for (int m = 8; m >= 1; m >>= 1) {
            a += __shfl_xor(a, m, 64);
            c += __shfl_xor(c, m, 64);
        }
        if (col == 0) {
            int o = o0 + (wo << 4) + (rowg << 2) + r;
            atomicAdd(&ssum[o], a);
            atomicAdd(&ssq[o], c);
        }
    }
}

// ---------------- zero stats / finalize BN ----------------------------------
__global__ __launch_bounds__(256) void k_zero(float* __restrict__ p, int n) {
    int i = blockIdx.x * 256 + threadIdx.x;
    if (i < n) p[i] = 0.f;
}
__global__ __launch_bounds__(256) void k_bnfin(const float* __restrict__ ssum,
                                               const float* __restrict__ ssq,
                                               const float* __restrict__ g,
                                               const float* __restrict__ beta,
                                               float* __restrict__ scale,
                                               float* __restrict__ shift, int C) {
    int c = blockIdx.x * 256 + threadIdx.x;
    if (c >= C) return;
    float M = (float)(B_ * N_);
    float mean = ssum[c] / M;
    float var = ssq[c] / M - mean * mean;
    float sc = g[c] / sqrtf(var + 1e-5f);
    scale[c] = sc;
    shift[c] = beta[c] - mean * sc;
}

// ---------------- final BN2 + ReLU, in-place over d_out ---------------------
__global__ __launch_bounds__(256) void k_final(float* __restrict__ buf,
                                               const float* __restrict__ scale,
                                               const float* __restrict__ shift) {
    size_t total = (size_t)B_ * C_ * N_;
    for (size_t idx = (size_t)blockIdx.x * 256 + threadIdx.x; idx < total;
         idx += (size_t)gridDim.x * 256) {
        int c = (int)((idx / N_) % C_);
        buf[idx] = fmaxf(buf[idx] * scale[c] + shift[c], 0.f);
    }
}

extern "C" void kernel_launch(void* const* d_in, const int* in_sizes, int n_in,
                              void* d_out, int out_size, void* d_ws, size_t ws_size,
                              hipStream_t stream) {
    (void)in_sizes; (void)n_in; (void)out_size;
    const float* x    = (const float*)d_in[0];
    const float* qw   = (const float*)d_in[1];
    const float* qb   = (const float*)d_in[2];
    const float* kw   = (const float*)d_in[3];
    const float* kb   = (const float*)d_in[4];
    const float* vw   = (const float*)d_in[5];
    const float* vb   = (const float*)d_in[6];
    const float* fcw  = (const float*)d_in[7];
    const float* fcb  = (const float*)d_in[8];
    const float* c1w  = (const float*)d_in[9];
    const float* c1b  = (const float*)d_in[10];
    const float* bn1g = (const float*)d_in[11];
    const float* bn1b = (const float*)d_in[12];
    const float* c2w  = (const float*)d_in[13];
    const float* c2b  = (const float*)d_in[14];
    const float* bn2g = (const float*)d_in[15];
    const float* bn2b = (const float*)d_in[16];
    const void*  gam  = d_in[17];

    // ---- adaptive layout: mode A = full-batch fcout bf16; mode B = per-group
    const size_t WSF = ws_size / sizeof(float);
    const size_t NC = (size_t)N_ * C_;          // 75264
    const size_t fixedA = 9633792 + 2408448 + 165888 + 165888 + 50176 + 50176 + 1024 + 1920 + 256;
    const size_t fixedB = 2408448 + 165888 + 165888 + 50176 + 50176 + 1024 + 1920 + 256;
    const int tiers[7] = {64, 32, 16, 8, 4, 2, 1};
    int GB = 0; bool modeA = false;
    for (int t = 0; t < 6; ++t) {
        size_t need = fixedA + (size_t)tiers[t] * (2 * NC + (size_t)N_ * N_ + N_);
        if (need <= WSF) { GB = tiers[t]; modeA = true; break; }
    }
    if (!modeA) {
        for (int t = 0; t < 7; ++t) {
            size_t need = fixedB + (size_t)tiers[t] * (2 * NC + (size_t)N_ * N_ + N_ + NC / 2 + 16);
            if (need <= WSF) { GB = tiers[t]; break; }
        }
        if (GB == 0) GB = 1;
    }

    float* wsf = (float*)d_ws;
    size_t off = 0;
    unsigned short* fcout_bf = nullptr;
    if (modeA) { fcout_bf = (unsigned short*)(wsf + off); off += 9633792; }
    unsigned short* y1_bf = (unsigned short*)(wsf + off); off += 2408448;   // B*196*96 bf16
    unsigned short* W1 = (unsigned short*)(wsf + off); off += 165888;       // 96*3456 bf16
    unsigned short* W2 = (unsigned short*)(wsf + off); off += 165888;       // 384*864 bf16
    float* mA   = wsf + off; off += 50176;
    float* mB   = wsf + off; off += 50176;
    float* swin = wsf + off; off += 1024;
    float* stats = wsf + off; off += 1920;
    float* ssum1 = stats,        *ssq1 = stats + 96;
    float* ssum2 = stats + 192,  *ssq2 = stats + 576;
    float* scale1 = stats + 960, *shift1 = stats + 1056;
    float* scale2 = stats + 1152,*shift2 = stats + 1536;
    off += 256;  // pad
    float* qh    = wsf + off; off += (size_t)GB * NC;
    float* kh    = wsf + off; off += (size_t)GB * NC;
    float* attnh = wsf + off; off += (size_t)GB * N_ * N_;
    float* spah  = wsf + off; off += (size_t)GB * N_;
    unsigned short* fcg = nullptr;
    if (!modeA) { fcg = (unsigned short*)(wsf + off); off += (size_t)GB * NC / 2 + 16; }

    float* yout = (float*)d_out;

    k_zero<<<dim3(4), 256, 0, stream>>>(stats, 960);
    k_wprep<<<dim3(2592), 256, 0, stream>>>(c1w, c2w, W1, W2);
    k_winsel<<<dim3(B_ * 4), 256, 0, stream>>>(x, swin);
    k_mask<<<dim3(B_), 256, 0, stream>>>(swin, gam, mA, mB);

    for (int b0 = 0; b0 < B_; b0 += GB) {
        const float* xg = x + (size_t)b0 * C_ * N_;
        k_qkv<<<dim3(GB, 4, 6), 256, 0, stream>>>(xg, qw, qb, mA + (size_t)b0 * N_, qh);
        k_qkv<<<dim3(GB, 4, 6), 256, 0, stream>>>(xg, kw, kb, mB + (size_t)b0 * N_, kh);
        k_attn<<<dim3(GB, 4, 4), 256, 0, stream>>>(qh, kh, attnh);
        k_spa<<<dim3(GB * N_), 256, 0, stream>>>(attnh, spah);
        k_weight<<<dim3(GB * N_), 256, 0, stream>>>(attnh, spah);
        k_qkv<<<dim3(GB, 4, 6), 256, 0, stream>>>(xg, vw, vb, nullptr, qh);   // v
        k_feat<<<dim3(GB, 4, 6), 256, 0, stream>>>(attnh, qh, kh);            // feat
        unsigned short* fdst = modeA ? fcout_bf + (size_t)b0 * NC : fcg;
        k_fc<<<dim3(GB, 6, 4), 256, 0, stream>>>(kh, fcw, fcb, fdst);
        if (!modeA) {
            k_convm<384, 96, false, true><<<dim3(GB, 3), 256, 0, stream>>>(
                fcg, W1, c1b, nullptr, nullptr,
                y1_bf + (size_t)b0 * 196 * 96, nullptr, ssum1, ssq1);
        }
    }
    if (modeA) {
        k_convm<384, 96, false, true><<<dim3(B_, 3), 256, 0, stream>>>(
            fcout_bf, W1, c1b, nullptr, nullptr, y1_bf, nullptr, ssum1, ssq1);
    }
    k_bnfin<<<dim3(1), 256, 0, stream>>>(ssum1, ssq1, bn1g, bn1b, scale1, shift1, 96);
    k_convm<96, 384, true, false><<<dim3(B_, 12), 256, 0, stream>>>(
        y1_bf, W2, c2b, scale1, shift1, nullptr, yout, ssum2, ssq2);
    k_bnfin<<<dim3(2), 256, 0, stream>>>(ssum2, ssq2, bn2g, bn2b, scale2, shift2, 384);
    k_final<<<dim3(18816), 256, 0, stream>>>(yout, scale2, shift2);
}

// Round 6
// 2851.016 us; speedup vs baseline: 2.5369x; 1.3680x over previous
//
#include <hip/hip_runtime.h>

static constexpr int B_ = 256;
static constexpr int C_ = 384;
static constexpr int N_ = 196;   // 14*14
static constexpr int H_ = 14;
static constexpr int CH_ = 96;
static constexpr int PW_ = 49;
static constexpr int NPAIR_ = 1225;

using bf8 = __attribute__((ext_vector_type(8))) short;   // 8 bf16
using f4  = __attribute__((ext_vector_type(4))) float;   // 4 f32

__device__ __forceinline__ float bf2f(unsigned short u) {
    unsigned int x = ((unsigned int)u) << 16;
    return __builtin_bit_cast(float, x);
}
__device__ __forceinline__ unsigned short f2bf(float f) {
    unsigned int x = __builtin_bit_cast(unsigned int, f);
    x = x + 0x7FFFu + ((x >> 16) & 1u);   // RNE
    return (unsigned short)(x >> 16);
}

// ---------------- window selection: s[b,w] = sum triu(cos) -------------------
__global__ __launch_bounds__(256) void k_winsel(const float* __restrict__ x,
                                                float* __restrict__ swin) {
    int blk = blockIdx.x;
    int b = blk >> 2, wi = blk & 3;
    int hr = (wi >> 1) * 7, wc0 = (wi & 1) * 7;
    __shared__ float xs[128 * PW_];
    __shared__ float dots[NPAIR_];
    __shared__ float nrm[PW_];
    __shared__ float red[256];
    int tid = threadIdx.x;
    int pi[5], pj[5];
    int nm = 0;
    for (int p = tid; p < NPAIR_; p += 256) {
        int pp = p, i = 0;
        while (pp >= PW_ - i) { pp -= PW_ - i; ++i; }
        pi[nm] = i; pj[nm] = i + pp; ++nm;
    }
    float acc[5] = {0.f, 0.f, 0.f, 0.f, 0.f};
    for (int c0 = 0; c0 < C_; c0 += 128) {
        __syncthreads();
        for (int e = tid; e < 128 * PW_; e += 256) {
            int cc = e / PW_, i = e - cc * PW_;
            int h = hr + i / 7, w = wc0 + i % 7;
            xs[e] = x[((b * C_ + c0 + cc) * H_ + h) * H_ + w];
        }
        __syncthreads();
        for (int cc = 0; cc < 128; ++cc) {
            const float* row = &xs[cc * PW_];
            #pragma unroll
            for (int t = 0; t < 5; ++t)
                if (t < nm) acc[t] = fmaf(row[pi[t]], row[pj[t]], acc[t]);
        }
    }
    for (int t = 0; t < nm; ++t) dots[tid + t * 256] = acc[t];
    __syncthreads();
    if (tid < PW_) {
        int diag = tid * PW_ - tid * (tid - 1) / 2;
        nrm[tid] = sqrtf(dots[diag]);
    }
    __syncthreads();
    float part = 0.f;
    for (int t = 0; t < nm; ++t) {
        float den = fmaxf(nrm[pi[t]] * nrm[pj[t]], 1e-8f);
        part += dots[tid + t * 256] / den;
    }
    red[tid] = part;
    __syncthreads();
    for (int st = 128; st > 0; st >>= 1) {
        if (tid < st) red[tid] += red[tid + st];
        __syncthreads();
    }
    if (tid == 0) swin[blk] = red[0];
}

// ---------------- top-2 windows -> masks ------------------------------------
__global__ __launch_bounds__(256) void k_mask(const float* __restrict__ swin,
                                              const void* __restrict__ gammp,
                                              float* __restrict__ mA,
                                              float* __restrict__ mB) {
    int b = blockIdx.x;
    float sv[4];
    #pragma unroll
    for (int i = 0; i < 4; ++i) sv[i] = swin[b * 4 + i];
    int i0 = 0; float bv = sv[0];
    #pragma unroll
    for (int i = 1; i < 4; ++i) if (sv[i] > bv) { bv = sv[i]; i0 = i; }
    int i1 = -1; float bv1 = -1e30f;
    #pragma unroll
    for (int i = 0; i < 4; ++i) {
        if (i == i0) continue;
        if (sv[i] > bv1) { bv1 = sv[i]; i1 = i; }
    }
    int iv = *(const int*)gammp;
    float g = (iv == 1) ? 1.0f : __int_as_float(iv);
    int n = threadIdx.x;
    if (n < N_) {
        int h = n / 14, w = n - h * 14;
        int widx = ((h >= 7) ? 2 : 0) + ((w >= 7) ? 1 : 0);
        bool member = (widx == i0) || (widx == i1);
        float a = member ? 0.f : 1.f;
        float bm = 1.f - a;
        if (b == 0) { a = g; bm = g; }
        mA[b * N_ + n] = a;
        mB[b * N_ + n] = bm;
    }
}

// -- q/k: out[bl,n,o] = m[bl,n]*(sum_c x[bl,c,n]*W[o,c]) + bias[o] (fp32) ----
__global__ __launch_bounds__(256) void k_qkv(const float* __restrict__ x,
                                             const float* __restrict__ W,
                                             const float* __restrict__ bias,
                                             const float* __restrict__ mask,
                                             float* __restrict__ out) {
    int b = blockIdx.x, n0 = blockIdx.y * 64, o0 = blockIdx.z * 64;
    __shared__ float xs[16][65];
    __shared__ float ws[64][17];
    int tid = threadIdx.x, tx = tid & 15, ty = tid >> 4;
    float acc[4][4] = {};
    for (int c0 = 0; c0 < C_; c0 += 16) {
        __syncthreads();
        for (int e = tid; e < 1024; e += 256) {
            int cc = e >> 6, nn = e & 63;
            int n = n0 + nn;
            xs[cc][nn] = (n < N_) ? x[(b * C_ + c0 + cc) * N_ + n] : 0.f;
        }
        for (int e = tid; e < 1024; e += 256) {
            int oo = e >> 4, cc = e & 15;
            ws[oo][cc] = W[(o0 + oo) * C_ + c0 + cc];
        }
        __syncthreads();
        #pragma unroll
        for (int cc = 0; cc < 16; ++cc) {
            float a[4], bb[4];
            #pragma unroll
            for (int i = 0; i < 4; ++i) a[i] = xs[cc][ty * 4 + i];
            #pragma unroll
            for (int j = 0; j < 4; ++j) bb[j] = ws[tx * 4 + j][cc];
            #pragma unroll
            for (int i = 0; i < 4; ++i)
                #pragma unroll
                for (int j = 0; j < 4; ++j) acc[i][j] = fmaf(a[i], bb[j], acc[i][j]);
        }
    }
    #pragma unroll
    for (int i = 0; i < 4; ++i) {
        int n = n0 + ty * 4 + i;
        if (n >= N_) continue;
        float m = mask ? mask[b * N_ + n] : 1.f;
        #pragma unroll
        for (int j = 0; j < 4; ++j) {
            int o = o0 + tx * 4 + j;
            out[(b * N_ + n) * C_ + o] = m * acc[i][j] + bias[o];
        }
    }
}

// ---------------- attn[bl,i,j] = sum_c q[bl,i,c]*k[bl,j,c] (fp32) -----------
__global__ __launch_bounds__(256) void k_attn(const float* __restrict__ q,
                                              const float* __restrict__ k,
                                              float* __restrict__ attn) {
    int b = blockIdx.x, i0 = blockIdx.y * 64, j0 = blockIdx.z * 64;
    __shared__ float qs[64][17];
    __shared__ float ks[64][17];
    int tid = threadIdx.x, tx = tid & 15, ty = tid >> 4;
    float acc[4][4] = {};
    for (int c0 = 0; c0 < C_; c0 += 16) {
        __syncthreads();
        for (int e = tid; e < 1024; e += 256) {
            int r = e >> 4, cc = e & 15;
            int i = i0 + r;
            qs[r][cc] = (i < N_) ? q[(b * N_ + i) * C_ + c0 + cc] : 0.f;
            int j = j0 + r;
            ks[r][cc] = (j < N_) ? k[(b * N_ + j) * C_ + c0 + cc] : 0.f;
        }
        __syncthreads();
        #pragma unroll
        for (int cc = 0; cc < 16; ++cc) {
            float a[4], bb[4];
            #pragma unroll
            for (int i = 0; i < 4; ++i) a[i] = qs[ty * 4 + i][cc];
            #pragma unroll
            for (int j = 0; j < 4; ++j) bb[j] = ks[tx * 4 + j][cc];
            #pragma unroll
            for (int i = 0; i < 4; ++i)
                #pragma unroll
                for (int j = 0; j < 4; ++j) acc[i][j] = fmaf(a[i], bb[j], acc[i][j]);
        }
    }
    #pragma unroll
    for (int i = 0; i < 4; ++i) {
        int ii = i0 + ty * 4 + i;
        if (ii >= N_) continue;
        #pragma unroll
        for (int j = 0; j < 4; ++j) {
            int jj = j0 + tx * 4 + j;
            if (jj < N_) attn[(b * N_ + ii) * N_ + jj] = acc[i][j];
        }
    }
}

// ---------------- spa[row] = mean_j attn[row, j] ----------------------------
__global__ __launch_bounds__(256) void k_spa(const float* __restrict__ attn,
                                             float* __restrict__ spa) {
    int row = blockIdx.x;
    const float* rp = attn + (size_t)row * N_;
    int t = threadIdx.x;
    float v = (t < N_) ? rp[t] : 0.f;
    __shared__ float red[256];
    red[t] = v; __syncthreads();
    for (int st = 128; st > 0; st >>= 1) {
        if (t < st) red[t] += red[t + st];
        __syncthreads();
    }
    if (t == 0) spa[row] = red[0] / (float)N_;
}

// --------- spatial-sim weight -> bf16 wbf[row][224] (196 valid, pad 0) ------
__global__ __launch_bounds__(256) void k_weight(const float* __restrict__ attn,
                                                const float* __restrict__ spa,
                                                unsigned short* __restrict__ wbf) {
    int row = blockIdx.x;            // bl*196 + i
    int b = row / N_, i = row - b * N_;
    int t = threadIdx.x;
    __shared__ float osp[N_];
    __shared__ float red[256];
    __shared__ float lastsh;
    float myspa = spa[row];
    float o = 0.f;
    if (t < N_) { o = fabsf(myspa - spa[b * N_ + t]); osp[t] = o; }
    __syncthreads();
    if (t < N_) {
        int cgt = 0, ceq = 0;
        for (int j = 0; j < N_; ++j) {
            float oj = osp[j];
            cgt += (oj > o) ? 1 : 0;
            ceq += (oj == o) ? 1 : 0;
        }
        if (cgt <= 97 && cgt + ceq >= 98) lastsh = o;
    }
    __syncthreads();
    float last = lastsh;
    const float* rowp = attn + (size_t)row * N_;
    float s = (t < N_) ? rowp[t] : 0.f;
    float a1 = -1e30f, a2 = -1e30f;
    if (t < N_) {
        float of = o + ((t == i) ? 10000.f : 0.f);
        float o1 = (of < last) ? 0.f : 1.f;
        float o2 = (o1 > last) ? 0.f : 1.f;
        float w1 = o1 * s;
        float w2 = o2 * s;
        a1 = (w1 == 0.f) ? -100.f : w1;
        a2 = (w2 == 0.f) ? -100.f : w2;
    }
    red[t] = a1; __syncthreads();
    for (int st = 128; st > 0; st >>= 1) {
        if (t < st) red[t] = fmaxf(red[t], red[t + st]);
        __syncthreads();
    }
    float m1 = red[0]; __syncthreads();
    float e1 = (t < N_) ? expf(a1 - m1) : 0.f;
    red[t] = e1; __syncthreads();
    for (int st = 128; st > 0; st >>= 1) {
        if (t < st) red[t] += red[t + st];
        __syncthreads();
    }
    float S1 = red[0]; __syncthreads();
    red[t] = a2; __syncthreads();
    for (int st = 128; st > 0; st >>= 1) {
        if (t < st) red[t] = fmaxf(red[t], red[t + st]);
        __syncthreads();
    }
    float m2 = red[0]; __syncthreads();
    float e2 = (t < N_) ? expf(a2 - m2) : 0.f;
    red[t] = e2; __syncthreads();
    for (int st = 128; st > 0; st >>= 1) {
        if (t < st) red[t] += red[t + st];
        __syncthreads();
    }
    float S2 = red[0]; __syncthreads();
    if (t < 224)
        wbf[(size_t)row * 224 + t] = (t < N_) ? f2bf(e1 / S1 + e2 / S2) : (unsigned short)0;
}

// ---------------- weight/param prep to bf16 ---------------------------------
// W1p[((q*9+tap)*96 + o)*32 + k]  from c1w[o][c=q*32+k][tap]
// W2p[((q*9+tap)*384 + o)*32 + k] from c2w[o][c=q*32+k][tap]
// vwb  = bf16(vw), fcwb = bf16(fcw)
__global__ __launch_bounds__(256) void k_wprep(const float* __restrict__ c1w,
                                               const float* __restrict__ c2w,
                                               const float* __restrict__ vw,
                                               const float* __restrict__ fcw,
                                               unsigned short* __restrict__ W1p,
                                               unsigned short* __restrict__ W2p,
                                               unsigned short* __restrict__ vwb,
                                               unsigned short* __restrict__ fcwb) {
    int i = blockIdx.x * 256 + threadIdx.x;
    if (i < 331776) {   // 12*9*96*32
        int qt = i >> 5, k = i & 31;
        int q = qt / (9 * 96); int r = qt - q * 9 * 96;
        int tap = r / 96, o = r - tap * 96;
        W1p[i] = f2bf(c1w[(o * 384 + q * 32 + k) * 9 + tap]);
        return;
    }
    i -= 331776;
    if (i < 331776) {   // 3*9*384*32
        int qt = i >> 5, k = i & 31;
        int q = qt / (9 * 384); int r = qt - q * 9 * 384;
        int tap = r / 384, o = r - tap * 384;
        W2p[i] = f2bf(c2w[(o * 96 + q * 32 + k) * 9 + tap]);
        return;
    }
    i -= 331776;
    if (i < 147456) { vwb[i] = f2bf(vw[i]); return; }
    i -= 147456;
    if (i < 147456) { fcwb[i] = f2bf(fcw[i]); }
}

// ============ MFMA conv 3x3, stage-once per 32-ch chunk, 9-tap reuse ========
// TRANS=false (conv1): in = NHWC bf16 [b][196][CIN]; out = bf16 [b][COUT][196]
// TRANS=true  (conv2): in = CHW  bf16 [b][CIN][196], BN1(scale,shift)+ReLU
//                      applied during staging; out = f32 [b][COUT][196]
template <int CIN, int COUT, bool TRANS>
__global__ __launch_bounds__(256) void k_convm(
    const unsigned short* __restrict__ in,
    const unsigned short* __restrict__ Wg,
    const float* __restrict__ cb,
    const float* __restrict__ scale,
    const float* __restrict__ shift,
    unsigned short* __restrict__ outb,
    float* __restrict__ outf,
    float* __restrict__ ssum, float* __restrict__ ssq) {
    constexpr int CPT = CIN / 32;
    __shared__ unsigned short Bs[197 * 40];   // [px][32ch], 80B row stride
    int b = blockIdx.x, o0 = blockIdx.y * 32;
    int tid = threadIdx.x, lane = tid & 63, wid = tid >> 6;
    int col = lane & 15, rowg = lane >> 4;

    if (tid < 10) *(unsigned long long*)&Bs[196 * 40 + tid * 4] = 0ull;

    int a0[4], vb[4];
    #pragma unroll
    for (int f = 0; f < 4; ++f) {
        int px = wid * 64 + f * 16 + col;
        int h = px / 14, w = px - h * 14;
        a0[f] = px * 80 + rowg * 16;
        int m = 0;
        #pragma unroll
        for (int tap = 0; tap < 9; ++tap) {
            int dh = tap / 3 - 1, dw = tap % 3 - 1;
            if (px < 196 && (unsigned)(h + dh) < 14u && (unsigned)(w + dw) < 14u)
                m |= 1 << tap;
        }
        vb[f] = m;
    }
    const int zaddr = 196 * 80 + rowg * 16;
    const int doff[9] = {-15 * 80, -14 * 80, -13 * 80, -80, 0, 80, 13 * 80, 14 * 80, 15 * 80};

    f4 acc[4][2];
    #pragma unroll
    for (int f = 0; f < 4; ++f) { acc[f][0] = (f4){0,0,0,0}; acc[f][1] = (f4){0,0,0,0}; }

    int c4 = (tid & 7) << 2, pxs = tid >> 3;
    int cpair = tid & 15, qd0 = tid >> 4;

    for (int kq = 0; kq < CPT; ++kq) {
        __syncthreads();
        if constexpr (!TRANS) {
            #pragma unroll
            for (int i = 0; i < 7; ++i) {
                int px = pxs + 32 * i;
                if (px < 196)
                    *(unsigned long long*)&Bs[px * 40 + c4] =
                        *(const unsigned long long*)&in[((size_t)b * 196 + px) * CIN + kq * 32 + c4];
            }
        } else {
            int ch = kq * 32 + 2 * cpair;
            float s0 = scale[ch], s1 = scale[ch + 1];
            float h0 = shift[ch], h1 = shift[ch + 1];
            const unsigned short* r0 = in + ((size_t)b * CIN + ch) * 196;
            const unsigned short* r1 = r0 + 196;
            #pragma unroll
            for (int qi = 0; qi < 4; ++qi) {
                int quad = qd0 + 16 * qi;
                if (quad < 49) {
                    unsigned long long ra = *(const unsigned long long*)&r0[quad * 4];
                    unsigned long long rb = *(const unsigned long long*)&r1[quad * 4];
                    #pragma unroll
                    for (int j = 0; j < 4; ++j) {
                        float v0 = fmaxf(fmaf(bf2f((unsigned short)(ra >> (16 * j))), s0, h0), 0.f);
                        float v1 = fmaxf(fmaf(bf2f((unsigned short)(rb >> (16 * j))), s1, h1), 0.f);
                        unsigned int pk = (unsigned int)f2bf(v0) | ((unsigned int)f2bf(v1) << 16);
                        *(unsigned int*)&Bs[(quad * 4 + j) * 40 + cpair * 2] = pk;
                    }
                }
            }
        }
        __syncthreads();
        #pragma unroll
        for (int tap = 0; tap < 9; ++tap) {
            const unsigned short* wp =
                Wg + ((size_t)((kq * 9 + tap) * COUT) + o0 + col) * 32 + rowg * 8;
            bf8 af0 = *(const bf8*)wp;
            bf8 af1 = *(const bf8*)(wp + 16 * 32);
            #pragma unroll
            for (int f = 0; f < 4; ++f) {
                int ba = ((vb[f] >> tap) & 1) ? a0[f] + doff[tap] : zaddr;
                bf8 bv = *(const bf8*)((const char*)Bs + ba);
                acc[f][0] = __builtin_amdgcn_mfma_f32_16x16x32_bf16(af0, bv, acc[f][0], 0, 0, 0);
                acc[f][1] = __builtin_amdgcn_mfma_f32_16x16x32_bf16(af1, bv, acc[f][1], 0, 0, 0);
            }
        }
    }

    float bias[2][4], s1a[2][4] = {}, s2a[2][4] = {};
    #pragma unroll
    for (int oh = 0; oh < 2; ++oh)
        #pragma unroll
        for (int r = 0; r < 4; ++r) bias[oh][r] = cb[o0 + oh * 16 + rowg * 4 + r];
    #pragma unroll
    for (int f = 0; f < 4; ++f) {
        int px = wid * 64 + f * 16 + col;
        bool pv = px < 196;
        #pragma unroll
        for (int oh = 0; oh < 2; ++oh)
            #pragma unroll
            for (int r = 0; r < 4; ++r) {
                float val = acc[f][oh][r] + bias[oh][r];
                if (pv) {
                    int o = o0 + oh * 16 + rowg * 4 + r;
                    if constexpr (!TRANS)
                        outb[((size_t)b * COUT + o) * 196 + px] = f2bf(val);
                    else
                        outf[((size_t)b * COUT + o) * 196 + px] = val;
                    s1a[oh][r] += val;
                    s2a[oh][r] += val * val;
                }
            }
    }
    #pragma unroll
    for (int oh = 0; oh < 2; ++oh)
        #pragma unroll
        for (int r = 0; r < 4; ++r) {
            float a = s1a[oh][r], c = s2a[oh][r];
            #pragma unroll
            for (int m = 8; m >= 1; m >>= 1) {
                a += __shfl_xor(a, m, 64);
                c += __shfl_xor(c, m, 64);
            }
            if (col == 0) {
                int o = o0 + oh * 16 + rowg * 4 + r;
                atomicAdd(&ssum[o], a);
                atomicAdd(&ssq[o], c);
            }
        }
}

// ============ MFMA GEMM: out[b][m<196][384] = A[b][196][K] * Bm[N][K]^T =====
// A bf16 staged in LDS; Bm fragments direct from global (L2). Optional col bias.
template <int K, bool BIASCOL>
__global__ __launch_bounds__(256) void k_gemm_nt(
    const unsigned short* __restrict__ A,
    const unsigned short* __restrict__ Bm, long bstrB,
    const float* __restrict__ biasc,
    unsigned short* __restrict__ out) {
    __shared__ unsigned short Bs[197 * 40];
    int b = blockIdx.x, c0 = blockIdx.y * 32;
    int tid = threadIdx.x, lane = tid & 63, wid = tid >> 6;
    int col = lane & 15, rowg = lane >> 4;
    const unsigned short* Ab = A + (size_t)b * 196 * K;
    const unsigned short* Bb = Bm + (size_t)b * bstrB;

    if (tid < 10) *(unsigned long long*)&Bs[196 * 40 + tid * 4] = 0ull;
    int a0[4]; bool pv[4];
    #pragma unroll
    for (int f = 0; f < 4; ++f) {
        int px = wid * 64 + f * 16 + col;
        a0[f] = px * 80 + rowg * 16;
        pv[f] = px < 196;
    }
    const int zaddr = 196 * 80 + rowg * 16;
    f4 acc[4][2];
    #pragma unroll
    for (int f = 0; f < 4; ++f) { acc[f][0] = (f4){0,0,0,0}; acc[f][1] = (f4){0,0,0,0}; }
    int c4 = (tid & 7) << 2, pxs = tid >> 3;

    for (int kq = 0; kq < K / 32; ++kq) {
        __syncthreads();
        #pragma unroll
        for (int i = 0; i < 7; ++i) {
            int px = pxs + 32 * i;
            if (px < 196)
                *(unsigned long long*)&Bs[px * 40 + c4] =
                    *(const unsigned long long*)&Ab[(size_t)px * K + kq * 32 + c4];
        }
        __syncthreads();
        const unsigned short* bp = Bb + (size_t)(c0 + col) * K + kq * 32 + rowg * 8;
        bf8 b0 = *(const bf8*)bp;
        bf8 b1 = *(const bf8*)(bp + (size_t)16 * K);
        #pragma unroll
        for (int f = 0; f < 4; ++f) {
            int ba = pv[f] ? a0[f] : zaddr;
            bf8 av = *(const bf8*)((const char*)Bs + ba);
            acc[f][0] = __builtin_amdgcn_mfma_f32_16x16x32_bf16(av, b0, acc[f][0], 0, 0, 0);
            acc[f][1] = __builtin_amdgcn_mfma_f32_16x16x32_bf16(av, b1, acc[f][1], 0, 0, 0);
        }
    }
    float bc[2] = {0.f, 0.f};
    if constexpr (BIASCOL) { bc[0] = biasc[c0 + col]; bc[1] = biasc[c0 + 16 + col]; }
    #pragma unroll
    for (int f = 0; f < 4; ++f) {
        #pragma unroll
        for (int oh = 0; oh < 2; ++oh)
            #pragma unroll
            for (int r = 0; r < 4; ++r) {
                int m = wid * 64 + f * 16 + rowg * 4 + r;
                if (m < 196)
                    out[((size_t)b * 196 + m) * 384 + c0 + oh * 16 + col] =
                        f2bf(acc[f][oh][r] + bc[oh]);
            }
    }
}

// ============ MFMA v-proj: vt[b][o][n(224)] = (x^T @ vw^T)^T + vb ===========
// x f32 CHW staged transposed->bf16 in LDS; vw fragments direct from global.
__global__ __launch_bounds__(256) void k_gemm_v(
    const float* __restrict__ x,
    const unsigned short* __restrict__ vwb,
    const float* __restrict__ vbias,
    unsigned short* __restrict__ vt) {
    __shared__ unsigned short Bs[197 * 40];
    int b = blockIdx.x, o0 = blockIdx.y * 32;
    int tid = threadIdx.x, lane = tid & 63, wid = tid >> 6;
    int col = lane & 15, rowg = lane >> 4;

    if (tid < 10) *(unsigned long long*)&Bs[196 * 40 + tid * 4] = 0ull;
    int a0[4]; bool pv[4];
    #pragma unroll
    for (int f = 0; f < 4; ++f) {
        int px = wid * 64 + f * 16 + col;
        a0[f] = px * 80 + rowg * 16;
        pv[f] = px < 196;
    }
    const int zaddr = 196 * 80 + rowg * 16;
    f4 acc[4][2];
    #pragma unroll
    for (int f = 0; f < 4; ++f) { acc[f][0] = (f4){0,0,0,0}; acc[f][1] = (f4){0,0,0,0}; }
    int cpair = tid & 15, qd0 = tid >> 4;

    for (int kq = 0; kq < 12; ++kq) {
        __syncthreads();
        const float* r0 = x + ((size_t)b * 384 + kq * 32 + 2 * cpair) * 196;
        const float* r1 = r0 + 196;
        #pragma unroll
        for (int qi = 0; qi < 4; ++qi) {
            int quad = qd0 + 16 * qi;
            if (quad < 49) {
                float4 ra = *(const float4*)&r0[quad * 4];
                float4 rb = *(const float4*)&r1[quad * 4];
                float av[4] = {ra.x, ra.y, ra.z, ra.w};
                float bv[4] = {rb.x, rb.y, rb.z, rb.w};
                #pragma unroll
                for (int j = 0; j < 4; ++j) {
                    unsigned int pk = (unsigned int)f2bf(av[j]) | ((unsigned int)f2bf(bv[j]) << 16);
                    *(unsigned int*)&Bs[(quad * 4 + j) * 40 + cpair * 2] = pk;
                }
            }
        }
        __syncthreads();
        const unsigned short* wp = vwb + (size_t)(o0 + col) * 384 + kq * 32 + rowg * 8;
        bf8 w0 = *(const bf8*)wp;
        bf8 w1 = *(const bf8*)(wp + 16 * 384);
        #pragma unroll
        for (int f = 0; f < 4; ++f) {
            int ba = pv[f] ? a0[f] : zaddr;
            bf8 av = *(const bf8*)((const char*)Bs + ba);
            acc[f][0] = __builtin_amdgcn_mfma_f32_16x16x32_bf16(w0, av, acc[f][0], 0, 0, 0);
            acc[f][1] = __builtin_amdgcn_mfma_f32_16x16x32_bf16(w1, av, acc[f][1], 0, 0, 0);
        }
    }
    float bia[2][4];
    #pragma unroll
    for (int oh = 0; oh < 2; ++oh)
        #pragma unroll
        for (int r = 0; r < 4; ++r) bia[oh][r] = vbias[o0 + oh * 16 + rowg * 4 + r];
    #pragma unroll
    for (int f = 0; f < 4; ++f) {
        int n = wid * 64 + f * 16 + col;
        if (n >= 224) continue;
        #pragma unroll
        for (int oh = 0; oh < 2; ++oh)
            #pragma unroll
            for (int r = 0; r < 4; ++r) {
                int o = o0 + oh * 16 + rowg * 4 + r;
                vt[((size_t)b * 384 + o) * 224 + n] =
                    (n < 196) ? f2bf(acc[f][oh][r] + bia[oh][r]) : (unsigned short)0;
            }
    }
}

// ---------------- zero stats / finalize BN ----------------------------------
__global__ __launch_bounds__(256) void k_zero(float* __restrict__ p, int n) {
    int i = blockIdx.x * 256 + threadIdx.x;
    if (i < n) p[i] = 0.f;
}
__global__ __launch_bounds__(256) void k_bnfin(const float* __restrict__ ssum,
                                               const float* __restrict__ ssq,
                                               const float* __restrict__ g,
                                               const float* __restrict__ beta,
                                               float* __restrict__ scale,
                                               float* __restrict__ shift, int C) {
    int c = blockIdx.x * 256 + threadIdx.x;
    if (c >= C) return;
    float M = (float)(B_ * N_);
    float mean = ssum[c] / M;
    float var = ssq[c] / M - mean * mean;
    float sc = g[c] / sqrtf(var + 1e-5f);
    scale[c] = sc;
    shift[c] = beta[c] - mean * sc;
}

// ---------------- final BN2 + ReLU, in-place over d_out ---------------------
__global__ __launch_bounds__(256) void k_final(float* __restrict__ buf,
                                               const float* __restrict__ scale,
                                               const float* __restrict__ shift) {
    size_t total = (size_t)B_ * C_ * N_;
    for (size_t idx = (size_t)blockIdx.x * 256 + threadIdx.x; idx < total;
         idx += (size_t)gridDim.x * 256) {
        int c = (int)((idx / N_) % C_);
        buf[idx] = fmaxf(buf[idx] * scale[c] + shift[c], 0.f);
    }
}

extern "C" void kernel_launch(void* const* d_in, const int* in_sizes, int n_in,
                              void* d_out, int out_size, void* d_ws, size_t ws_size,
                              hipStream_t stream) {
    (void)in_sizes; (void)n_in; (void)out_size;
    const float* x    = (const float*)d_in[0];
    const float* qw   = (const float*)d_in[1];
    const float* qb   = (const float*)d_in[2];
    const float* kw   = (const float*)d_in[3];
    const float* kb   = (const float*)d_in[4];
    const float* vw   = (const float*)d_in[5];
    const float* vb   = (const float*)d_in[6];
    const float* fcw  = (const float*)d_in[7];
    const float* fcb  = (const float*)d_in[8];
    const float* c1w  = (const float*)d_in[9];
    const float* c1b  = (const float*)d_in[10];
    const float* bn1g = (const float*)d_in[11];
    const float* bn1b = (const float*)d_in[12];
    const float* c2w  = (const float*)d_in[13];
    const float* c2b  = (const float*)d_in[14];
    const float* bn2g = (const float*)d_in[15];
    const float* bn2b = (const float*)d_in[16];
    const void*  gam  = d_in[17];

    const size_t WSF = ws_size / sizeof(float);
    // fixed buffers (floats) — F_Y1 = B*96*196 bf16 = 4,816,896 shorts = 2,408,448 floats
    const size_t F_Y1 = 2408448;
    const size_t F_W1 = 165888, F_W2 = 165888, F_VW = 73728, F_FW = 73728;
    const size_t F_MA = 50176, F_MB = 50176, F_SW = 1024, F_ST = 1920;
    const size_t fixedF = F_Y1 + F_W1 + F_W2 + F_VW + F_FW + F_MA + F_MB + F_SW + F_ST + 512;
    // per-batch group floats: qh + kh + attn + spa + wbf/2 + vt/2 + featb/2 + fcout/2
    const size_t perB = 75264 + 75264 + 38416 + 196 + 21952 + 43008 + 37632 + 37632 + 64;
    const int tiers[7] = {64, 32, 16, 8, 4, 2, 1};
    int GB = 1;
    for (int t = 0; t < 7; ++t) {
        if (fixedF + (size_t)tiers[t] * perB <= WSF) { GB = tiers[t]; break; }
    }

    float* wsf = (float*)d_ws;
    size_t off = 0;
    unsigned short* y1   = (unsigned short*)(wsf + off); off += F_Y1;
    unsigned short* W1p  = (unsigned short*)(wsf + off); off += F_W1;
    unsigned short* W2p  = (unsigned short*)(wsf + off); off += F_W2;
    unsigned short* vwb  = (unsigned short*)(wsf + off); off += F_VW;
    unsigned short* fcwb = (unsigned short*)(wsf + off); off += F_FW;
    float* mA   = wsf + off; off += F_MA;
    float* mB   = wsf + off; off += F_MB;
    float* swin = wsf + off; off += F_SW;
    float* stats = wsf + off; off += F_ST + 512;
    float* ssum1 = stats,         *ssq1 = stats + 96;
    float* ssum2 = stats + 192,   *ssq2 = stats + 576;
    float* scale1 = stats + 960,  *shift1 = stats + 1056;
    float* scale2 = stats + 1152, *shift2 = stats + 1536;
    float* qh    = wsf + off; off += (size_t)GB * 75264;
    float* kh    = wsf + off; off += (size_t)GB * 75264;
    float* attnh = wsf + off; off += (size_t)GB * 38416;
    float* spah  = wsf + off; off += (size_t)GB * 196 + 64;
    unsigned short* wbf   = (unsigned short*)(wsf + off); off += (size_t)GB * 21952;
    unsigned short* vt    = (unsigned short*)(wsf + off); off += (size_t)GB * 43008;
    unsigned short* featb = (unsigned short*)(wsf + off); off += (size_t)GB * 37632;
    unsigned short* fcoutg = (unsigned short*)(wsf + off); off += (size_t)GB * 37632;

    float* yout = (float*)d_out;

    k_zero<<<dim3(4), 256, 0, stream>>>(stats, 960);
    k_wprep<<<dim3(3744), 256, 0, stream>>>(c1w, c2w, vw, fcw, W1p, W2p, vwb, fcwb);
    k_winsel<<<dim3(B_ * 4), 256, 0, stream>>>(x, swin);
    k_mask<<<dim3(B_), 256, 0, stream>>>(swin, gam, mA, mB);

    for (int b0 = 0; b0 < B_; b0 += GB) {
        const float* xg = x + (size_t)b0 * C_ * N_;
        k_qkv<<<dim3(GB, 4, 6), 256, 0, stream>>>(xg, qw, qb, mA + (size_t)b0 * N_, qh);
        k_qkv<<<dim3(GB, 4, 6), 256, 0, stream>>>(xg, kw, kb, mB + (size_t)b0 * N_, kh);
        k_attn<<<dim3(GB, 4, 4), 256, 0, stream>>>(qh, kh, attnh);
        k_spa<<<dim3(GB * N_), 256, 0, stream>>>(attnh, spah);
        k_weight<<<dim3(GB * N_), 256, 0, stream>>>(attnh, spah, wbf);
        k_gemm_v<<<dim3(GB, 12), 256, 0, stream>>>(xg, vwb, vb, vt);
        k_gemm_nt<224, false><<<dim3(GB, 12), 256, 0, stream>>>(
            wbf, vt, 86016L, nullptr, featb);
        k_gemm_nt<384, true><<<dim3(GB, 12), 256, 0, stream>>>(
            featb, fcwb, 0L, fcb, fcoutg);
        k_convm<384, 96, false><<<dim3(GB, 3), 256, 0, stream>>>(
            fcoutg, W1p, c1b, nullptr, nullptr,
            y1 + (size_t)b0 * CH_ * N_, nullptr, ssum1, ssq1);
    }
    k_bnfin<<<dim3(1), 256, 0, stream>>>(ssum1, ssq1, bn1g, bn1b, scale1, shift1, 96);
    k_convm<96, 384, true><<<dim3(B_, 12), 256, 0, stream>>>(
        y1, W2p, c2b, scale1, shift1, nullptr, yout, ssum2, ssq2);
    k_bnfin<<<dim3(2), 256, 0, stream>>>(ssum2, ssq2, bn2g, bn2b, scale2, shift2, 384);
    k_final<<<dim3(18816), 256, 0, stream>>>(yout, scale2, shift2);
}

// Round 9
// 2729.823 us; speedup vs baseline: 2.6495x; 1.0444x over previous
//
#include <hip/hip_runtime.h>

static constexpr int B_ = 256;
static constexpr int C_ = 384;
static constexpr int N_ = 196;   // 14*14
static constexpr int H_ = 14;
static constexpr int CH_ = 96;
static constexpr int PW_ = 49;
static constexpr int NPAIR_ = 1225;

using bf8 = __attribute__((ext_vector_type(8))) short;   // 8 bf16
using f4  = __attribute__((ext_vector_type(4))) float;   // 4 f32

__device__ __forceinline__ float bf2f(unsigned short u) {
    unsigned int x = ((unsigned int)u) << 16;
    return __builtin_bit_cast(float, x);
}
__device__ __forceinline__ unsigned short f2bf(float f) {
    unsigned int x = __builtin_bit_cast(unsigned int, f);
    x = x + 0x7FFFu + ((x >> 16) & 1u);   // RNE
    return (unsigned short)(x >> 16);
}

// ---------------- window selection: s[b,w] = sum triu(cos) -------------------
__global__ __launch_bounds__(256) void k_winsel(const float* __restrict__ x,
                                                float* __restrict__ swin) {
    int blk = blockIdx.x;
    int b = blk >> 2, wi = blk & 3;
    int hr = (wi >> 1) * 7, wc0 = (wi & 1) * 7;
    __shared__ float xs[128 * PW_];
    __shared__ float dots[NPAIR_];
    __shared__ float nrm[PW_];
    __shared__ float red[256];
    int tid = threadIdx.x;
    int pi[5], pj[5];
    int nm = 0;
    for (int p = tid; p < NPAIR_; p += 256) {
        int pp = p, i = 0;
        while (pp >= PW_ - i) { pp -= PW_ - i; ++i; }
        pi[nm] = i; pj[nm] = i + pp; ++nm;
    }
    float acc[5] = {0.f, 0.f, 0.f, 0.f, 0.f};
    for (int c0 = 0; c0 < C_; c0 += 128) {
        __syncthreads();
        for (int e = tid; e < 128 * PW_; e += 256) {
            int cc = e / PW_, i = e - cc * PW_;
            int h = hr + i / 7, w = wc0 + i % 7;
            xs[e] = x[((b * C_ + c0 + cc) * H_ + h) * H_ + w];
        }
        __syncthreads();
        for (int cc = 0; cc < 128; ++cc) {
            const float* row = &xs[cc * PW_];
            #pragma unroll
            for (int t = 0; t < 5; ++t)
                if (t < nm) acc[t] = fmaf(row[pi[t]], row[pj[t]], acc[t]);
        }
    }
    for (int t = 0; t < nm; ++t) dots[tid + t * 256] = acc[t];
    __syncthreads();
    if (tid < PW_) {
        int diag = tid * PW_ - tid * (tid - 1) / 2;
        nrm[tid] = sqrtf(dots[diag]);
    }
    __syncthreads();
    float part = 0.f;
    for (int t = 0; t < nm; ++t) {
        float den = fmaxf(nrm[pi[t]] * nrm[pj[t]], 1e-8f);
        part += dots[tid + t * 256] / den;
    }
    red[tid] = part;
    __syncthreads();
    for (int st = 128; st > 0; st >>= 1) {
        if (tid < st) red[tid] += red[tid + st];
        __syncthreads();
    }
    if (tid == 0) swin[blk] = red[0];
}

// ---------------- top-2 windows -> masks ------------------------------------
__global__ __launch_bounds__(256) void k_mask(const float* __restrict__ swin,
                                              const void* __restrict__ gammp,
                                              float* __restrict__ mA,
                                              float* __restrict__ mB) {
    int b = blockIdx.x;
    float sv[4];
    #pragma unroll
    for (int i = 0; i < 4; ++i) sv[i] = swin[b * 4 + i];
    int i0 = 0; float bv = sv[0];
    #pragma unroll
    for (int i = 1; i < 4; ++i) if (sv[i] > bv) { bv = sv[i]; i0 = i; }
    int i1 = -1; float bv1 = -1e30f;
    #pragma unroll
    for (int i = 0; i < 4; ++i) {
        if (i == i0) continue;
        if (sv[i] > bv1) { bv1 = sv[i]; i1 = i; }
    }
    int iv = *(const int*)gammp;
    float g = (iv == 1) ? 1.0f : __int_as_float(iv);
    int n = threadIdx.x;
    if (n < N_) {
        int h = n / 14, w = n - h * 14;
        int widx = ((h >= 7) ? 2 : 0) + ((w >= 7) ? 1 : 0);
        bool member = (widx == i0) || (widx == i1);
        float a = member ? 0.f : 1.f;
        float bm = 1.f - a;
        if (b == 0) { a = g; bm = g; }
        mA[b * N_ + n] = a;
        mB[b * N_ + n] = bm;
    }
}

// -- q/k: out[bl,n,o] = m[bl,n]*(sum_c x[bl,c,n]*W[o,c]) + bias[o] (fp32) ----
__global__ __launch_bounds__(256) void k_qkv(const float* __restrict__ x,
                                             const float* __restrict__ W,
                                             const float* __restrict__ bias,
                                             const float* __restrict__ mask,
                                             float* __restrict__ out) {
    int b = blockIdx.x, n0 = blockIdx.y * 64, o0 = blockIdx.z * 64;
    __shared__ float xs[16][65];
    __shared__ float ws[64][17];
    int tid = threadIdx.x, tx = tid & 15, ty = tid >> 4;
    float acc[4][4] = {};
    for (int c0 = 0; c0 < C_; c0 += 16) {
        __syncthreads();
        for (int e = tid; e < 1024; e += 256) {
            int cc = e >> 6, nn = e & 63;
            int n = n0 + nn;
            xs[cc][nn] = (n < N_) ? x[(b * C_ + c0 + cc) * N_ + n] : 0.f;
        }
        for (int e = tid; e < 1024; e += 256) {
            int oo = e >> 4, cc = e & 15;
            ws[oo][cc] = W[(o0 + oo) * C_ + c0 + cc];
        }
        __syncthreads();
        #pragma unroll
        for (int cc = 0; cc < 16; ++cc) {
            float a[4], bb[4];
            #pragma unroll
            for (int i = 0; i < 4; ++i) a[i] = xs[cc][ty * 4 + i];
            #pragma unroll
            for (int j = 0; j < 4; ++j) bb[j] = ws[tx * 4 + j][cc];
            #pragma unroll
            for (int i = 0; i < 4; ++i)
                #pragma unroll
                for (int j = 0; j < 4; ++j) acc[i][j] = fmaf(a[i], bb[j], acc[i][j]);
        }
    }
    #pragma unroll
    for (int i = 0; i < 4; ++i) {
        int n = n0 + ty * 4 + i;
        if (n >= N_) continue;
        float m = mask ? mask[b * N_ + n] : 1.f;
        #pragma unroll
        for (int j = 0; j < 4; ++j) {
            int o = o0 + tx * 4 + j;
            out[(b * N_ + n) * C_ + o] = m * acc[i][j] + bias[o];
        }
    }
}

// ---------------- attn[bl,i,j] = sum_c q[bl,i,c]*k[bl,j,c] (fp32) -----------
__global__ __launch_bounds__(256) void k_attn(const float* __restrict__ q,
                                              const float* __restrict__ k,
                                              float* __restrict__ attn) {
    int b = blockIdx.x, i0 = blockIdx.y * 64, j0 = blockIdx.z * 64;
    __shared__ float qs[64][17];
    __shared__ float ks[64][17];
    int tid = threadIdx.x, tx = tid & 15, ty = tid >> 4;
    float acc[4][4] = {};
    for (int c0 = 0; c0 < C_; c0 += 16) {
        __syncthreads();
        for (int e = tid; e < 1024; e += 256) {
            int r = e >> 4, cc = e & 15;
            int i = i0 + r;
            qs[r][cc] = (i < N_) ? q[(b * N_ + i) * C_ + c0 + cc] : 0.f;
            int j = j0 + r;
            ks[r][cc] = (j < N_) ? k[(b * N_ + j) * C_ + c0 + cc] : 0.f;
        }
        __syncthreads();
        #pragma unroll
        for (int cc = 0; cc < 16; ++cc) {
            float a[4], bb[4];
            #pragma unroll
            for (int i = 0; i < 4; ++i) a[i] = qs[ty * 4 + i][cc];
            #pragma unroll
            for (int j = 0; j < 4; ++j) bb[j] = ks[tx * 4 + j][cc];
            #pragma unroll
            for (int i = 0; i < 4; ++i)
                #pragma unroll
                for (int j = 0; j < 4; ++j) acc[i][j] = fmaf(a[i], bb[j], acc[i][j]);
        }
    }
    #pragma unroll
    for (int i = 0; i < 4; ++i) {
        int ii = i0 + ty * 4 + i;
        if (ii >= N_) continue;
        #pragma unroll
        for (int j = 0; j < 4; ++j) {
            int jj = j0 + tx * 4 + j;
            if (jj < N_) attn[(b * N_ + ii) * N_ + jj] = acc[i][j];
        }
    }
}

// ---------------- spa[row] = mean_j attn[row, j] ----------------------------
__global__ __launch_bounds__(256) void k_spa(const float* __restrict__ attn,
                                             float* __restrict__ spa) {
    int row = blockIdx.x;
    const float* rp = attn + (size_t)row * N_;
    int t = threadIdx.x;
    float v = (t < N_) ? rp[t] : 0.f;
    __shared__ float red[256];
    red[t] = v; __syncthreads();
    for (int st = 128; st > 0; st >>= 1) {
        if (t < st) red[t] += red[t + st];
        __syncthreads();
    }
    if (t == 0) spa[row] = red[0] / (float)N_;
}

// --------- spatial-sim weight -> bf16 wbf[row][224] (196 valid, pad 0) ------
__global__ __launch_bounds__(256) void k_weight(const float* __restrict__ attn,
                                                const float* __restrict__ spa,
                                                unsigned short* __restrict__ wbf) {
    int row = blockIdx.x;            // bl*196 + i
    int b = row / N_, i = row - b * N_;
    int t = threadIdx.x;
    __shared__ float osp[N_];
    __shared__ float red[256];
    __shared__ float lastsh;
    float myspa = spa[row];
    float o = 0.f;
    if (t < N_) { o = fabsf(myspa - spa[b * N_ + t]); osp[t] = o; }
    __syncthreads();
    if (t < N_) {
        int cgt = 0, ceq = 0;
        for (int j = 0; j < N_; ++j) {
            float oj = osp[j];
            cgt += (oj > o) ? 1 : 0;
            ceq += (oj == o) ? 1 : 0;
        }
        if (cgt <= 97 && cgt + ceq >= 98) lastsh = o;
    }
    __syncthreads();
    float last = lastsh;
    const float* rowp = attn + (size_t)row * N_;
    float s = (t < N_) ? rowp[t] : 0.f;
    float a1 = -1e30f, a2 = -1e30f;
    if (t < N_) {
        float of = o + ((t == i) ? 10000.f : 0.f);
        float o1 = (of < last) ? 0.f : 1.f;
        float o2 = (o1 > last) ? 0.f : 1.f;
        float w1 = o1 * s;
        float w2 = o2 * s;
        a1 = (w1 == 0.f) ? -100.f : w1;
        a2 = (w2 == 0.f) ? -100.f : w2;
    }
    red[t] = a1; __syncthreads();
    for (int st = 128; st > 0; st >>= 1) {
        if (t < st) red[t] = fmaxf(red[t], red[t + st]);
        __syncthreads();
    }
    float m1 = red[0]; __syncthreads();
    float e1 = (t < N_) ? expf(a1 - m1) : 0.f;
    red[t] = e1; __syncthreads();
    for (int st = 128; st > 0; st >>= 1) {
        if (t < st) red[t] += red[t + st];
        __syncthreads();
    }
    float S1 = red[0]; __syncthreads();
    red[t] = a2; __syncthreads();
    for (int st = 128; st > 0; st >>= 1) {
        if (t < st) red[t] = fmaxf(red[t], red[t + st]);
        __syncthreads();
    }
    float m2 = red[0]; __syncthreads();
    float e2 = (t < N_) ? expf(a2 - m2) : 0.f;
    red[t] = e2; __syncthreads();
    for (int st = 128; st > 0; st >>= 1) {
        if (t < st) red[t] += red[t + st];
        __syncthreads();
    }
    float S2 = red[0]; __syncthreads();
    if (t < 224)
        wbf[(size_t)row * 224 + t] = (t < N_) ? f2bf(e1 / S1 + e2 / S2) : (unsigned short)0;
}

// ---------------- weight/param prep to bf16 ---------------------------------
__global__ __launch_bounds__(256) void k_wprep(const float* __restrict__ c1w,
                                               const float* __restrict__ c2w,
                                               const float* __restrict__ vw,
                                               const float* __restrict__ fcw,
                                               unsigned short* __restrict__ W1p,
                                               unsigned short* __restrict__ W2p,
                                               unsigned short* __restrict__ vwb,
                                               unsigned short* __restrict__ fcwb) {
    int i = blockIdx.x * 256 + threadIdx.x;
    if (i < 331776) {   // 12*9*96*32
        int qt = i >> 5, k = i & 31;
        int q = qt / (9 * 96); int r = qt - q * 9 * 96;
        int tap = r / 96, o = r - tap * 96;
        W1p[i] = f2bf(c1w[(o * 384 + q * 32 + k) * 9 + tap]);
        return;
    }
    i -= 331776;
    if (i < 331776) {   // 3*9*384*32
        int qt = i >> 5, k = i & 31;
        int q = qt / (9 * 384); int r = qt - q * 9 * 384;
        int tap = r / 384, o = r - tap * 384;
        W2p[i] = f2bf(c2w[(o * 96 + q * 32 + k) * 9 + tap]);
        return;
    }
    i -= 331776;
    if (i < 147456) { vwb[i] = f2bf(vw[i]); return; }
    i -= 147456;
    if (i < 147456) { fcwb[i] = f2bf(fcw[i]); }
}

// ============ MFMA conv 3x3, stage-once per 32-ch chunk, 9-tap reuse ========
// A-weights staged in LDS per chunk (removes global-load dep from MFMA chain).
// TRANS=false (conv1): in = NHWC bf16 [b][196][CIN]; out = bf16 [b][COUT][196]
// TRANS=true  (conv2): in = CHW  bf16 [b][CIN][196], BN1+ReLU during staging;
//                      out = f32 [b][COUT][196]
template <int CIN, int COUT, bool TRANS>
__global__ __launch_bounds__(256) void k_convm(
    const unsigned short* __restrict__ in,
    const unsigned short* __restrict__ Wg,
    const float* __restrict__ cb,
    const float* __restrict__ scale,
    const float* __restrict__ shift,
    unsigned short* __restrict__ outb,
    float* __restrict__ outf,
    float* __restrict__ ssum, float* __restrict__ ssq) {
    constexpr int CPT = CIN / 32;
    __shared__ unsigned short Bs[197 * 40];     // [px][32ch], 80B row stride
    __shared__ unsigned short As[9 * 32 * 36];  // [tap*32+o][32k], 72B row stride
    int b = blockIdx.x, o0 = blockIdx.y * 32;
    int tid = threadIdx.x, lane = tid & 63, wid = tid >> 6;
    int col = lane & 15, rowg = lane >> 4;

    if (tid < 10) *(unsigned long long*)&Bs[196 * 40 + tid * 4] = 0ull;

    int a0[4], vb[4];
    #pragma unroll
    for (int f = 0; f < 4; ++f) {
        int px = wid * 64 + f * 16 + col;
        int h = px / 14, w = px - h * 14;
        a0[f] = px * 80 + rowg * 16;
        int m = 0;
        #pragma unroll
        for (int tap = 0; tap < 9; ++tap) {
            int dh = tap / 3 - 1, dw = tap % 3 - 1;
            if (px < 196 && (unsigned)(h + dh) < 14u && (unsigned)(w + dw) < 14u)
                m |= 1 << tap;
        }
        vb[f] = m;
    }
    const int zaddr = 196 * 80 + rowg * 16;
    const int doff[9] = {-15 * 80, -14 * 80, -13 * 80, -80, 0, 80, 13 * 80, 14 * 80, 15 * 80};

    f4 acc[4][2];
    #pragma unroll
    for (int f = 0; f < 4; ++f) { acc[f][0] = (f4){0,0,0,0}; acc[f][1] = (f4){0,0,0,0}; }

    int c4 = (tid & 7) << 2, pxs = tid >> 3;
    int cpair = tid & 15, qd0 = tid >> 4;

    for (int kq = 0; kq < CPT; ++kq) {
        __syncthreads();
        // ---- stage A: 9 taps x 32 o x 32 k (16B units) ----
        for (int u = tid; u < 1152; u += 256) {
            int r = u >> 2, part = u & 3;       // r = tap*32 + o
            int tap = r >> 5, o = r & 31;
            *(int4*)&As[r * 36 + part * 8] =
                *(const int4*)&Wg[((size_t)((kq * 9 + tap) * COUT) + o0 + o) * 32 + part * 8];
        }
        // ---- stage B ----
        if constexpr (!TRANS) {
            #pragma unroll
            for (int i = 0; i < 7; ++i) {
                int px = pxs + 32 * i;
                if (px < 196)
                    *(unsigned long long*)&Bs[px * 40 + c4] =
                        *(const unsigned long long*)&in[((size_t)b * 196 + px) * CIN + kq * 32 + c4];
            }
        } else {
            int ch = kq * 32 + 2 * cpair;
            float s0 = scale[ch], s1 = scale[ch + 1];
            float h0 = shift[ch], h1 = shift[ch + 1];
            const unsigned short* r0 = in + ((size_t)b * CIN + ch) * 196;
            const unsigned short* r1 = r0 + 196;
            #pragma unroll
            for (int qi = 0; qi < 4; ++qi) {
                int quad = qd0 + 16 * qi;
                if (quad < 49) {
                    unsigned long long ra = *(const unsigned long long*)&r0[quad * 4];
                    unsigned long long rb = *(const unsigned long long*)&r1[quad * 4];
                    #pragma unroll
                    for (int j = 0; j < 4; ++j) {
                        float v0 = fmaxf(fmaf(bf2f((unsigned short)(ra >> (16 * j))), s0, h0), 0.f);
                        float v1 = fmaxf(fmaf(bf2f((unsigned short)(rb >> (16 * j))), s1, h1), 0.f);
                        unsigned int pk = (unsigned int)f2bf(v0) | ((unsigned int)f2bf(v1) << 16);
                        *(unsigned int*)&Bs[(quad * 4 + j) * 40 + cpair * 2] = pk;
                    }
                }
            }
        }
        __syncthreads();
        #pragma unroll
        for (int tap = 0; tap < 9; ++tap) {
            bf8 af0 = *(const bf8*)&As[(tap * 32 + col) * 36 + rowg * 8];
            bf8 af1 = *(const bf8*)&As[(tap * 32 + 16 + col) * 36 + rowg * 8];
            #pragma unroll
            for (int f = 0; f < 4; ++f) {
                int ba = ((vb[f] >> tap) & 1) ? a0[f] + doff[tap] : zaddr;
                bf8 bv = *(const bf8*)((const char*)Bs + ba);
                acc[f][0] = __builtin_amdgcn_mfma_f32_16x16x32_bf16(af0, bv, acc[f][0], 0, 0, 0);
                acc[f][1] = __builtin_amdgcn_mfma_f32_16x16x32_bf16(af1, bv, acc[f][1], 0, 0, 0);
            }
        }
    }

    float bias[2][4], s1a[2][4] = {}, s2a[2][4] = {};
    #pragma unroll
    for (int oh = 0; oh < 2; ++oh)
        #pragma unroll
        for (int r = 0; r < 4; ++r) bias[oh][r] = cb[o0 + oh * 16 + rowg * 4 + r];
    #pragma unroll
    for (int f = 0; f < 4; ++f) {
        int px = wid * 64 + f * 16 + col;
        bool pv = px < 196;
        #pragma unroll
        for (int oh = 0; oh < 2; ++oh)
            #pragma unroll
            for (int r = 0; r < 4; ++r) {
                float val = acc[f][oh][r] + bias[oh][r];
                if (pv) {
                    int o = o0 + oh * 16 + rowg * 4 + r;
                    if constexpr (!TRANS)
                        outb[((size_t)b * COUT + o) * 196 + px] = f2bf(val);
                    else
                        outf[((size_t)b * COUT + o) * 196 + px] = val;
                    s1a[oh][r] += val;
                    s2a[oh][r] += val * val;
                }
            }
    }
    #pragma unroll
    for (int oh = 0; oh < 2; ++oh)
        #pragma unroll
        for (int r = 0; r < 4; ++r) {
            float a = s1a[oh][r], c = s2a[oh][r];
            #pragma unroll
            for (int m = 8; m >= 1; m >>= 1) {
                a += __shfl_xor(a, m, 64);
                c += __shfl_xor(c, m, 64);
            }
            if (col == 0) {
                int o = o0 + oh * 16 + rowg * 4 + r;
                atomicAdd(&ssum[o], a);
                atomicAdd(&ssq[o], c);
            }
        }
}

// ============ MFMA GEMM: out[b][m<196][384] = A[b][196][K] * Bm[N][K]^T =====
template <int K, bool BIASCOL>
__global__ __launch_bounds__(256) void k_gemm_nt(
    const unsigned short* __restrict__ A,
    const unsigned short* __restrict__ Bm, long bstrB,
    const float* __restrict__ biasc,
    unsigned short* __restrict__ out) {
    __shared__ unsigned short Bs[197 * 40];
    int b = blockIdx.x, c0 = blockIdx.y * 32;
    int tid = threadIdx.x, lane = tid & 63, wid = tid >> 6;
    int col = lane & 15, rowg = lane >> 4;
    const unsigned short* Ab = A + (size_t)b * 196 * K;
    const unsigned short* Bb = Bm + (size_t)b * bstrB;

    if (tid < 10) *(unsigned long long*)&Bs[196 * 40 + tid * 4] = 0ull;
    int a0[4]; bool pv[4];
    #pragma unroll
    for (int f = 0; f < 4; ++f) {
        int px = wid * 64 + f * 16 + col;
        a0[f] = px * 80 + rowg * 16;
        pv[f] = px < 196;
    }
    const int zaddr = 196 * 80 + rowg * 16;
    f4 acc[4][2];
    #pragma unroll
    for (int f = 0; f < 4; ++f) { acc[f][0] = (f4){0,0,0,0}; acc[f][1] = (f4){0,0,0,0}; }
    int c4 = (tid & 7) << 2, pxs = tid >> 3;

    for (int kq = 0; kq < K / 32; ++kq) {
        __syncthreads();
        #pragma unroll
        for (int i = 0; i < 7; ++i) {
            int px = pxs + 32 * i;
            if (px < 196)
                *(unsigned long long*)&Bs[px * 40 + c4] =
                    *(const unsigned long long*)&Ab[(size_t)px * K + kq * 32 + c4];
        }
        __syncthreads();
        const unsigned short* bp = Bb + (size_t)(c0 + col) * K + kq * 32 + rowg * 8;
        bf8 b0 = *(const bf8*)bp;
        bf8 b1 = *(const bf8*)(bp + (size_t)16 * K);
        #pragma unroll
        for (int f = 0; f < 4; ++f) {
            int ba = pv[f] ? a0[f] : zaddr;
            bf8 av = *(const bf8*)((const char*)Bs + ba);
            acc[f][0] = __builtin_amdgcn_mfma_f32_16x16x32_bf16(av, b0, acc[f][0], 0, 0, 0);
            acc[f][1] = __builtin_amdgcn_mfma_f32_16x16x32_bf16(av, b1, acc[f][1], 0, 0, 0);
        }
    }
    float bc[2] = {0.f, 0.f};
    if constexpr (BIASCOL) { bc[0] = biasc[c0 + col]; bc[1] = biasc[c0 + 16 + col]; }
    #pragma unroll
    for (int f = 0; f < 4; ++f) {
        #pragma unroll
        for (int oh = 0; oh < 2; ++oh)
            #pragma unroll
            for (int r = 0; r < 4; ++r) {
                int m = wid * 64 + f * 16 + rowg * 4 + r;
                if (m < 196)
                    out[((size_t)b * 196 + m) * 384 + c0 + oh * 16 + col] =
                        f2bf(acc[f][oh][r] + bc[oh]);
            }
    }
}

// ============ MFMA v-proj: vt[b][o][n(224)] = (x^T @ vw^T)^T + vb ===========
__global__ __launch_bounds__(256) void k_gemm_v(
    const float* __restrict__ x,
    const unsigned short* __restrict__ vwb,
    const float* __restrict__ vbias,
    unsigned short* __restrict__ vt) {
    __shared__ unsigned short Bs[197 * 40];
    int b = blockIdx.x, o0 = blockIdx.y * 32;
    int tid = threadIdx.x, lane = tid & 63, wid = tid >> 6;
    int col = lane & 15, rowg = lane >> 4;

    if (tid < 10) *(unsigned long long*)&Bs[196 * 40 + tid * 4] = 0ull;
    int a0[4]; bool pv[4];
    #pragma unroll
    for (int f = 0; f < 4; ++f) {
        int px = wid * 64 + f * 16 + col;
        a0[f] = px * 80 + rowg * 16;
        pv[f] = px < 196;
    }
    const int zaddr = 196 * 80 + rowg * 16;
    f4 acc[4][2];
    #pragma unroll
    for (int f = 0; f < 4; ++f) { acc[f][0] = (f4){0,0,0,0}; acc[f][1] = (f4){0,0,0,0}; }
    int cpair = tid & 15, qd0 = tid >> 4;

    for (int kq = 0; kq < 12; ++kq) {
        __syncthreads();
        const float* r0 = x + ((size_t)b * 384 + kq * 32 + 2 * cpair) * 196;
        const float* r1 = r0 + 196;
        #pragma unroll
        for (int qi = 0; qi < 4; ++qi) {
            int quad = qd0 + 16 * qi;
            if (quad < 49) {
                float4 ra = *(const float4*)&r0[quad * 4];
                float4 rb = *(const float4*)&r1[quad * 4];
                float av[4] = {ra.x, ra.y, ra.z, ra.w};
                float bv[4] = {rb.x, rb.y, rb.z, rb.w};
                #pragma unroll
                for (int j = 0; j < 4; ++j) {
                    unsigned int pk = (unsigned int)f2bf(av[j]) | ((unsigned int)f2bf(bv[j]) << 16);
                    *(unsigned int*)&Bs[(quad * 4 + j) * 40 + cpair * 2] = pk;
                }
            }
        }
        __syncthreads();
        const unsigned short* wp = vwb + (size_t)(o0 + col) * 384 + kq * 32 + rowg * 8;
        bf8 w0 = *(const bf8*)wp;
        bf8 w1 = *(const bf8*)(wp + 16 * 384);
        #pragma unroll
        for (int f = 0; f < 4; ++f) {
            int ba = pv[f] ? a0[f] : zaddr;
            bf8 av = *(const bf8*)((const char*)Bs + ba);
            acc[f][0] = __builtin_amdgcn_mfma_f32_16x16x32_bf16(w0, av, acc[f][0], 0, 0, 0);
            acc[f][1] = __builtin_amdgcn_mfma_f32_16x16x32_bf16(w1, av, acc[f][1], 0, 0, 0);
        }
    }
    float bia[2][4];
    #pragma unroll
    for (int oh = 0; oh < 2; ++oh)
        #pragma unroll
        for (int r = 0; r < 4; ++r) bia[oh][r] = vbias[o0 + oh * 16 + rowg * 4 + r];
    #pragma unroll
    for (int f = 0; f < 4; ++f) {
        int n = wid * 64 + f * 16 + col;
        if (n >= 224) continue;
        #pragma unroll
        for (int oh = 0; oh < 2; ++oh)
            #pragma unroll
            for (int r = 0; r < 4; ++r) {
                int o = o0 + oh * 16 + rowg * 4 + r;
                vt[((size_t)b * 384 + o) * 224 + n] =
                    (n < 196) ? f2bf(acc[f][oh][r] + bia[oh][r]) : (unsigned short)0;
            }
    }
}

// ---------------- zero stats / finalize BN ----------------------------------
__global__ __launch_bounds__(256) void k_zero(float* __restrict__ p, int n) {
    int i = blockIdx.x * 256 + threadIdx.x;
    if (i < n) p[i] = 0.f;
}
__global__ __launch_bounds__(256) void k_bnfin(const float* __restrict__ ssum,
                                               const float* __restrict__ ssq,
                                               const float* __restrict__ g,
                                               const float* __restrict__ beta,
                                               float* __restrict__ scale,
                                               float* __restrict__ shift, int C) {
    int c = blockIdx.x * 256 + threadIdx.x;
    if (c >= C) return;
    float M = (float)(B_ * N_);
    float mean = ssum[c] / M;
    float var = ssq[c] / M - mean * mean;
    float sc = g[c] / sqrtf(var + 1e-5f);
    scale[c] = sc;
    shift[c] = beta[c] - mean * sc;
}

// ---------------- final BN2 + ReLU, in-place over d_out ---------------------
__global__ __launch_bounds__(256) void k_final(float* __restrict__ buf,
                                               const float* __restrict__ scale,
                                               const float* __restrict__ shift) {
    size_t total = (size_t)B_ * C_ * N_;
    for (size_t idx = (size_t)blockIdx.x * 256 + threadIdx.x; idx < total;
         idx += (size_t)gridDim.x * 256) {
        int c = (int)((idx / N_) % C_);
        buf[idx] = fmaxf(buf[idx] * scale[c] + shift[c], 0.f);
    }
}

extern "C" void kernel_launch(void* const* d_in, const int* in_sizes, int n_in,
                              void* d_out, int out_size, void* d_ws, size_t ws_size,
                              hipStream_t stream) {
    (void)in_sizes; (void)n_in; (void)out_size;
    const float* x    = (const float*)d_in[0];
    const float* qw   = (const float*)d_in[1];
    const float* qb   = (const float*)d_in[2];
    const float* kw   = (const float*)d_in[3];
    const float* kb   = (const float*)d_in[4];
    const float* vw   = (const float*)d_in[5];
    const float* vb   = (const float*)d_in[6];
    const float* fcw  = (const float*)d_in[7];
    const float* fcb  = (const float*)d_in[8];
    const float* c1w  = (const float*)d_in[9];
    const float* c1b  = (const float*)d_in[10];
    const float* bn1g = (const float*)d_in[11];
    const float* bn1b = (const float*)d_in[12];
    const float* c2w  = (const float*)d_in[13];
    const float* c2b  = (const float*)d_in[14];
    const float* bn2g = (const float*)d_in[15];
    const float* bn2b = (const float*)d_in[16];
    const void*  gam  = d_in[17];

    const size_t WSF = ws_size / sizeof(float);
    const size_t F_Y1 = 2408448;   // B*96*196 bf16 (in floats)
    const size_t F_W1 = 165888, F_W2 = 165888, F_VW = 73728, F_FW = 73728;
    const size_t F_MA = 50176, F_MB = 50176, F_SW = 1024, F_ST = 1920;
    const size_t F_FC = 9633792;   // full-batch fcout bf16 (in floats), modeA only
    const size_t fixedC = F_Y1 + F_W1 + F_W2 + F_VW + F_FW + F_MA + F_MB + F_SW + F_ST + 512;
    const size_t perA = 75264 + 75264 + 38416 + 196 + 64 + 21952 + 43008 + 37632;
    const size_t perBf = perA + 37632;   // modeB adds per-group fcoutg
    const int tiers[7] = {64, 32, 16, 8, 4, 2, 1};
    int GB = 0; bool modeA = false;
    for (int t = 0; t < 7; ++t) {
        if (fixedC + F_FC + (size_t)tiers[t] * perA <= WSF) { GB = tiers[t]; modeA = true; break; }
    }
    if (!modeA) {
        for (int t = 0; t < 7; ++t)
            if (fixedC + (size_t)tiers[t] * perBf <= WSF) { GB = tiers[t]; break; }
        if (GB == 0) GB = 1;
    }

    float* wsf = (float*)d_ws;
    size_t off = 0;
    unsigned short* y1   = (unsigned short*)(wsf + off); off += F_Y1;
    unsigned short* W1p  = (unsigned short*)(wsf + off); off += F_W1;
    unsigned short* W2p  = (unsigned short*)(wsf + off); off += F_W2;
    unsigned short* vwb  = (unsigned short*)(wsf + off); off += F_VW;
    unsigned short* fcwb = (unsigned short*)(wsf + off); off += F_FW;
    float* mA   = wsf + off; off += F_MA;
    float* mB   = wsf + off; off += F_MB;
    float* swin = wsf + off; off += F_SW;
    float* stats = wsf + off; off += F_ST + 512;
    float* ssum1 = stats,         *ssq1 = stats + 96;
    float* ssum2 = stats + 192,   *ssq2 = stats + 576;
    float* scale1 = stats + 960,  *shift1 = stats + 1056;
    float* scale2 = stats + 1152, *shift2 = stats + 1536;
    unsigned short* fcfull = nullptr;
    if (modeA) { fcfull = (unsigned short*)(wsf + off); off += F_FC; }
    float* qh    = wsf + off; off += (size_t)GB * 75264;
    float* kh    = wsf + off; off += (size_t)GB * 75264;
    float* attnh = wsf + off; off += (size_t)GB * 38416;
    float* spah  = wsf + off; off += (size_t)GB * 196 + 64;
    unsigned short* wbf   = (unsigned short*)(wsf + off); off += (size_t)GB * 21952;
    unsigned short* vt    = (unsigned short*)(wsf + off); off += (size_t)GB * 43008;
    unsigned short* featb = (unsigned short*)(wsf + off); off += (size_t)GB * 37632;
    unsigned short* fcoutg = nullptr;
    if (!modeA) { fcoutg = (unsigned short*)(wsf + off); off += (size_t)GB * 37632; }

    float* yout = (float*)d_out;

    k_zero<<<dim3(4), 256, 0, stream>>>(stats, 960);
    k_wprep<<<dim3(3744), 256, 0, stream>>>(c1w, c2w, vw, fcw, W1p, W2p, vwb, fcwb);
    k_winsel<<<dim3(B_ * 4), 256, 0, stream>>>(x, swin);
    k_mask<<<dim3(B_), 256, 0, stream>>>(swin, gam, mA, mB);

    for (int b0 = 0; b0 < B_; b0 += GB) {
        const float* xg = x + (size_t)b0 * C_ * N_;
        k_qkv<<<dim3(GB, 4, 6), 256, 0, stream>>>(xg, qw, qb, mA + (size_t)b0 * N_, qh);
        k_qkv<<<dim3(GB, 4, 6), 256, 0, stream>>>(xg, kw, kb, mB + (size_t)b0 * N_, kh);
        k_attn<<<dim3(GB, 4, 4), 256, 0, stream>>>(qh, kh, attnh);
        k_spa<<<dim3(GB * N_), 256, 0, stream>>>(attnh, spah);
        k_weight<<<dim3(GB * N_), 256, 0, stream>>>(attnh, spah, wbf);
        k_gemm_v<<<dim3(GB, 12), 256, 0, stream>>>(xg, vwb, vb, vt);
        k_gemm_nt<224, false><<<dim3(GB, 12), 256, 0, stream>>>(
            wbf, vt, 86016L, nullptr, featb);
        unsigned short* fdst = modeA ? (fcfull + (size_t)b0 * 75264) : fcoutg;
        k_gemm_nt<384, true><<<dim3(GB, 12), 256, 0, stream>>>(
            featb, fcwb, 0L, fcb, fdst);
        if (!modeA) {
            k_convm<384, 96, false><<<dim3(GB, 3), 256, 0, stream>>>(
                fcoutg, W1p, c1b, nullptr, nullptr,
                y1 + (size_t)b0 * CH_ * N_, nullptr, ssum1, ssq1);
        }
    }
    if (modeA) {
        k_convm<384, 96, false><<<dim3(B_, 3), 256, 0, stream>>>(
            fcfull, W1p, c1b, nullptr, nullptr, y1, nullptr, ssum1, ssq1);
    }
    k_bnfin<<<dim3(1), 256, 0, stream>>>(ssum1, ssq1, bn1g, bn1b, scale1, shift1, 96);
    k_convm<96, 384, true><<<dim3(B_, 12), 256, 0, stream>>>(
        y1, W2p, c2b, scale1, shift1, nullptr, yout, ssum2, ssq2);
    k_bnfin<<<dim3(2), 256, 0, stream>>>(ssum2, ssq2, bn2g, bn2b, scale2, shift2, 384);
    k_final<<<dim3(18816), 256, 0, stream>>>(yout, scale2, shift2);
}